// Round 13
// baseline (2185.105 us; speedup 1.0000x reference)
//
#include <hip/hip_runtime.h>

#define DEVINL __device__ __forceinline__

typedef unsigned short u16;
typedef __attribute__((ext_vector_type(8))) short v8s;   // 8 x bf16 (as raw i16)
typedef __attribute__((ext_vector_type(4))) short v4s;   // 4 x bf16 (8B)
typedef __attribute__((ext_vector_type(4))) float v4f;

static constexpr int Vn = 32000, En = 512, Hn = 1024, Bn = 32, Tn = 64;
static constexpr int FH = 4096;    // 4*H
static constexpr int MR = 2048;    // S*B == T*B
static constexpr int BH = Bn * Hn; // 32768

// ---------------- numeric helpers ----------------
DEVINL u16 f2bf(float x) {
    unsigned u = __float_as_uint(x);
    return (u16)((u + 0x7FFFu + ((u >> 16) & 1u)) >> 16);   // RNE to bf16
}
DEVINL float bf2f(u16 h) { return __uint_as_float(((unsigned)h) << 16); }
DEVINL void split2(float x, u16 &hi, u16 &lo) {
    u16 h = f2bf(x);
    hi = h;
    lo = f2bf(x - bf2f(h));
}
DEVINL float sigm(float x) { return 1.f / (1.f + __expf(-x)); }
DEVINL float tanh_fast(float x) { return 1.f - 2.f / (__expf(2.f * x) + 1.f); }
DEVINL v4f mf(v8s a, v8s b, v4f c) { return __builtin_amdgcn_mfma_f32_16x16x32_bf16(a, b, c, 0, 0, 0); }
DEVINL v8s cat8(v4s a, v4s b) { return __builtin_shufflevector(a, b, 0, 1, 2, 3, 4, 5, 6, 7); }

// async global->LDS, 16B per lane; LDS dest must be wave-uniform base (+lane*16 implicit)
DEVINL void gload_lds16(const u16* g, u16* l) {
    __builtin_amdgcn_global_load_lds((const __attribute__((address_space(1))) void*)g,
                                     (__attribute__((address_space(3))) void*)l, 16, 0, 0);
}

// ---------------- tiny prep kernels ----------------
// bar layout (u32, 64B-spaced lines):
//   flagsA: [16 + bid*16]              (h0[q] published -> flagA = pbase+q+1)
//   flagsB: [16 + 256*16 + bid*16]     (h1[q-1] published -> flagB = pbase+q+1)
static constexpr int BAR_U32 = 16 + 256 * 16 + 256 * 16;
__global__ void bar_init(unsigned* bar) {
    for (int i = threadIdx.x; i < BAR_U32; i += 256) bar[i] = 0u;
}

// gather embedding rows for [t*B+b] and split to bf16 hi/lo
__global__ void gather_split(const float* __restrict__ emb, const int* __restrict__ seq,
                             int isdec, u16* __restrict__ xh, u16* __restrict__ xl) {
    const int m = blockIdx.x;          // t*B + b
    const int b = m & 31, t = m >> 5;
    const int id = isdec ? (t == 0 ? 1 : seq[b * 64 + t - 1]) : seq[b * 64 + t];
    const float* src = emb + (size_t)id * En;
    for (int e = threadIdx.x; e < En; e += 256) {
        u16 h, l; split2(src[e], h, l);
        xh[(size_t)m * En + e] = h;
        xl[(size_t)m * En + e] = l;
    }
}

// fp32 -> bf16 hi (+ optional lo), vectorized x4
__global__ void split_w(const float* __restrict__ W, u16* __restrict__ hi,
                        u16* __restrict__ lo, int n4) {
    const int stride = gridDim.x * blockDim.x;
    for (int i = blockIdx.x * blockDim.x + threadIdx.x; i < n4; i += stride) {
        float4 x = ((const float4*)W)[i];
        u16 h0,h1,h2,h3,l0,l1,l2,l3;
        split2(x.x,h0,l0); split2(x.y,h1,l1); split2(x.z,h2,l2); split2(x.w,h3,l3);
        ushort4 hv; hv.x=h0; hv.y=h1; hv.z=h2; hv.w=h3;
        ((ushort4*)hi)[i] = hv;
        if (lo) { ushort4 lv; lv.x=l0; lv.y=l1; lv.z=l2; lv.w=l3; ((ushort4*)lo)[i] = lv; }
    }
}

// W [4096][1024] -> permuted split: dest row (j/4)*16 + q*4 + (j%4)
// scan block bid owns rows [bid*16, bid*16+16) = 4 units x 4 gates, local row = q*4+u
__global__ void perm_split(const float* __restrict__ Whh, u16* __restrict__ ph,
                           u16* __restrict__ pl) {
    const int g = blockIdx.x;                   // global gate row 0..4095
    const int q = g >> 10, j = g & 1023;
    const int dst = (j >> 2) * 16 + q * 4 + (j & 3);
    const int k4 = threadIdx.x;                 // 0..255 -> one float4 (1024/4)
    float4 x = ((const float4*)(Whh + (size_t)g * Hn))[k4];
    u16 h0,h1,h2,h3,l0,l1,l2,l3;
    split2(x.x,h0,l0); split2(x.y,h1,l1); split2(x.z,h2,l2); split2(x.w,h3,l3);
    ushort4 hv; hv.x=h0; hv.y=h1; hv.z=h2; hv.w=h3;
    ushort4 lv; lv.x=l0; lv.y=l1; lv.z=l2; lv.w=l3;
    ((ushort4*)(ph + (size_t)dst * Hn))[k4] = hv;
    ((ushort4*)(pl + (size_t)dst * Hn))[k4] = lv;
}

// block-major h [t][bid][cb][cu] -> row-major [m=t*32+b][k] for the FC GEMM
__global__ void unperm_h(const u16* __restrict__ ph, const u16* __restrict__ pl,
                         u16* __restrict__ oh, u16* __restrict__ ol) {
    const int m = blockIdx.x, t = m >> 5, b = m & 31;
    const int e = threadIdx.x;   // bid = e (1024/4 = 256 bids)
    const size_t src = (size_t)t * BH + (size_t)e * 128 + b * 4;
    const size_t dst = (size_t)m * Hn + (size_t)e * 4;
    *(v4s*)(oh + dst) = *(const v4s*)(ph + src);
    *(v4s*)(ol + dst) = *(const v4s*)(pl + src);
}

// ---------------- split-bf16 MFMA GEMM: C[M][N] = A[M][K] * B[N][K]^T + bias ----------------
// TERMS: 1 = Ahi*Bhi ; 2 = + Alo*Bhi ; 3 = + Ahi*Blo
// MODE:  0 = row-major C ; 1 = G-permute [bid][m][16] (r = u*4+q) ; 2 = FC remap [b][t][v]
// staging via global_load_lds width=16 (m97 lever) + bijective XCD blockIdx swizzle.
template<int TERMS, int MODE>
__global__ __launch_bounds__(256)
void gemm_bt(const u16* __restrict__ Ahi, const u16* __restrict__ Alo,
             const u16* __restrict__ Bhi, const u16* __restrict__ Blo,
             const float* __restrict__ bias1, const float* __restrict__ bias2,
             float* __restrict__ Cout, int M, int N, int K) {
    constexpr bool AL = (TERMS >= 2), BL = (TERMS >= 3);
    __shared__ __align__(16) u16 sAh[128 * 32];
    __shared__ __align__(16) u16 sBh[128 * 32];
    __shared__ __align__(16) u16 sAl[AL ? 128 * 32 : 8];
    __shared__ __align__(16) u16 sBl[BL ? 128 * 32 : 8];

    const int tid = threadIdx.x;
    const int lane = tid & 63, wave = tid >> 6;
    const int wr = wave >> 1, wc = wave & 1;
    // bijective XCD swizzle (nwg % 8 == 0 for all our grids)
    const int nwgx = gridDim.x;
    const int nwg = nwgx * gridDim.y;
    int wg = blockIdx.y * nwgx + blockIdx.x;
    wg = (wg & 7) * (nwg >> 3) + (wg >> 3);
    const int m0 = (wg / nwgx) * 128, n0 = (wg % nwgx) * 128;
    const int fr = lane & 15, fk = lane >> 4;

    v4f acc[4][4];
#pragma unroll
    for (int i = 0; i < 4; ++i)
#pragma unroll
        for (int j = 0; j < 4; ++j) acc[i][j] = (v4f){0.f, 0.f, 0.f, 0.f};

    // staging: 512 chunks of 16B per matrix; chunk c -> LDS byte c*16 (linear),
    // so the wave-uniform-dest constraint of global_load_lds is met exactly.
    const int c0 = tid, c1 = tid + 256;
    const int r0 = c0 >> 2, kg0 = c0 & 3, r1 = c1 >> 2, kg1 = c1 & 3;
    const int cw0 = (tid & ~63) * 8;          // wave-uniform LDS elem base, half 0
    const int cw1 = cw0 + 256 * 8;            // half 1

    for (int kk = 0; kk < K; kk += 32) {
        const size_t a0 = (size_t)(m0 + r0) * K + kk + kg0 * 8;
        const size_t a1 = (size_t)(m0 + r1) * K + kk + kg1 * 8;
        const size_t b0 = (size_t)(n0 + r0) * K + kk + kg0 * 8;
        const size_t b1 = (size_t)(n0 + r1) * K + kk + kg1 * 8;
        gload_lds16(Ahi + a0, sAh + cw0);
        gload_lds16(Ahi + a1, sAh + cw1);
        gload_lds16(Bhi + b0, sBh + cw0);
        gload_lds16(Bhi + b1, sBh + cw1);
        if constexpr (AL) {
            gload_lds16(Alo + a0, sAl + cw0);
            gload_lds16(Alo + a1, sAl + cw1);
        }
        if constexpr (BL) {
            gload_lds16(Blo + b0, sBl + cw0);
            gload_lds16(Blo + b1, sBl + cw1);
        }
        __syncthreads();   // drains vmcnt: all global_load_lds landed

        v8s ah[4], bh[4], al[4], bl[4];
#pragma unroll
        for (int mt = 0; mt < 4; ++mt) {
            const int row = wr * 64 + mt * 16 + fr;
            const int idx = row * 32 + fk * 8;
            ah[mt] = *(const v8s*)(sAh + idx);
            if constexpr (AL) al[mt] = *(const v8s*)(sAl + idx);
        }
#pragma unroll
        for (int nt = 0; nt < 4; ++nt) {
            const int row = wc * 64 + nt * 16 + fr;
            const int idx = row * 32 + fk * 8;
            bh[nt] = *(const v8s*)(sBh + idx);
            if constexpr (BL) bl[nt] = *(const v8s*)(sBl + idx);
        }
#pragma unroll
        for (int mt = 0; mt < 4; ++mt)
#pragma unroll
            for (int nt = 0; nt < 4; ++nt) {
                acc[mt][nt] = mf(ah[mt], bh[nt], acc[mt][nt]);
                if constexpr (AL) acc[mt][nt] = mf(al[mt], bh[nt], acc[mt][nt]);
                if constexpr (BL) acc[mt][nt] = mf(ah[mt], bl[nt], acc[mt][nt]);
            }
        __syncthreads();
    }

    // epilogue: D layout col = lane&15, row = (lane>>4)*4 + p  [m89-verified]
#pragma unroll
    for (int nt = 0; nt < 4; ++nt) {
        const int col = n0 + wc * 64 + nt * 16 + fr;
        float bsum = bias1 ? bias1[col] : 0.f;
        if (bias2) bsum += bias2[col];
#pragma unroll
        for (int mt = 0; mt < 4; ++mt) {
            const int rowb = m0 + wr * 64 + mt * 16 + fk * 4;
#pragma unroll
            for (int p = 0; p < 4; ++p) {
                const int row = rowb + p;
                const float v = acc[mt][nt][p] + bsum;
                if constexpr (MODE == 2) {
                    const int t = row >> 5, b = row & 31;
                    Cout[(size_t)b * ((size_t)Tn * Vn) + (size_t)t * Vn + col] = v;
                } else if constexpr (MODE == 1) {
                    const int q = col >> 10, j = col & 1023;
                    const int bidw = j >> 2, rloc = (j & 3) * 4 + q;
                    Cout[(size_t)bidw * ((size_t)MR * 16) + (size_t)row * 16 + rloc] = v;
                } else {
                    Cout[(size_t)row * N + col] = v;
                }
            }
        }
    }
}

// ---------------- decoupled-pipeline primitives (R13) ----------------
// Global flag poll: each lane checks 4 of the 256 producer flags (whole wave covers all).
// RELAXED loads; freshness by phase-unique data addresses (validated R2-R12).
DEVINL void poll4(unsigned* flags, unsigned tgt, int lane) {
#pragma unroll
    for (int j = 0; j < 4; ++j) {
        unsigned* p = flags + (size_t)(lane + j * 64) * 16;
        while (__hip_atomic_load(p, __ATOMIC_RELAXED, __HIP_MEMORY_SCOPE_AGENT) < tgt)
            __builtin_amdgcn_s_sleep(1);
    }
}
// LDS micro-barrier: RELEASE add (per-wave lgkmcnt drain covers all lanes' red writes),
// ACQUIRE spin (orders subsequent red reads / flag store).
DEVINL void lds_arrive(unsigned* c) {
    __hip_atomic_fetch_add(c, 1u, __ATOMIC_RELEASE, __HIP_MEMORY_SCOPE_WORKGROUP);
}
DEVINL void lds_spin(unsigned* c, unsigned tgt) {
    while (__hip_atomic_load(c, __ATOMIC_ACQUIRE, __HIP_MEMORY_SCOPE_WORKGROUP) < tgt)
        __builtin_amdgcn_s_sleep(0);
}

// ---- L0 weight pinning: 8 K-subtiles (K=256/wave), hi+lo = 16 v8s = 128 VGPRs.
#define DECLW8(P) v8s P##0, P##1, P##2, P##3, P##4, P##5, P##6, P##7
#define LOADW8(P, BASE) do { const u16* _b = (BASE) + woff; \
    P##0 = *(const v8s*)(_b);       P##1 = *(const v8s*)(_b + 32); \
    P##2 = *(const v8s*)(_b + 64);  P##3 = *(const v8s*)(_b + 96); \
    P##4 = *(const v8s*)(_b + 128); P##5 = *(const v8s*)(_b + 160); \
    P##6 = *(const v8s*)(_b + 192); P##7 = *(const v8s*)(_b + 224); } while (0)
#define PINW8(P) asm volatile("" : "+v"(P##0), "+v"(P##1), "+v"(P##2), "+v"(P##3), \
                                   "+v"(P##4), "+v"(P##5), "+v"(P##6), "+v"(P##7))

// block-major h fragment: h stored [t][bid][cb][cu]; lane (fr,fk) k-subtile K in a
// wave covering K-range w*256: bids {b0,b0+1}, b0 = w*64 + K*8 + fk*2.
#define LD8(B, B0, RO) cat8(*(const v4s*)((B) + (size_t)(B0) * 128 + (RO)), \
                            *(const v4s*)((B) + (size_t)(B0) * 128 + 128 + (RO)))

// L0 role: Whh0 only (pinned), 6 MFMA / subtile
#define KT0L(K) { \
    const int b0 = wave * 64 + K * 8 + fk * 2; \
    v8s hah = LD8(h0sh, b0, fr4); \
    v8s hal = LD8(h0sl, b0, fr4); \
    v8s hbh = LD8(h0sh, b0, fr4 + 64); \
    v8s hbl = LD8(h0sl, b0, fr4 + 64); \
    r0a = mf(hah, w0h_##K, r0a); r0a = mf(hal, w0h_##K, r0a); r0a = mf(hah, w0l_##K, r0a); \
    r0b = mf(hbh, w0h_##K, r0b); r0b = mf(hbl, w0h_##K, r0b); r0b = mf(hbh, w0l_##K, r0b); }

// tail role: Wih1 (streamed) x h0[q-1]
#define KTIH(K) { \
    const int b0 = w4 * 64 + K * 8 + fk * 2; \
    v8s wih = *(const v8s*)(WIh + woffT + K * 32); \
    v8s wil = *(const v8s*)(WIl + woffT + K * 32); \
    v8s hah = LD8(h0sh, b0, fr4); \
    v8s hal = LD8(h0sl, b0, fr4); \
    v8s hbh = LD8(h0sh, b0, fr4 + 64); \
    v8s hbl = LD8(h0sl, b0, fr4 + 64); \
    r1a = mf(hah, wih, r1a); r1a = mf(hal, wih, r1a); r1a = mf(hah, wil, r1a); \
    r1b = mf(hbh, wih, r1b); r1b = mf(hbl, wih, r1b); r1b = mf(hbh, wil, r1b); }

// tail role: Whh1 (streamed) x h1[q-2]
#define KTH1(K) { \
    const int b0 = w4 * 64 + K * 8 + fk * 2; \
    v8s w1h = *(const v8s*)(W1h + woffT + K * 32); \
    v8s w1l = *(const v8s*)(W1l + woffT + K * 32); \
    v8s hah = LD8(h1sh, b0, fr4); \
    v8s hal = LD8(h1sl, b0, fr4); \
    v8s hbh = LD8(h1sh, b0, fr4 + 64); \
    v8s hbl = LD8(h1sl, b0, fr4 + 64); \
    r1a = mf(hah, w1h, r1a); r1a = mf(hal, w1h, r1a); r1a = mf(hah, w1l, r1a); \
    r1b = mf(hbh, w1h, r1b); r1b = mf(hbl, w1h, r1b); r1b = mf(hbh, w1l, r1b); }

// ---------------- decoupled 2-layer LSTM scan (R13) ----------------
// R12 post-mortem: phase period = per-block SERIAL work; block-wide __syncthreads
// coupled all 8 waves into one chain. R13: NO __syncthreads in the loop.
//   Waves 0-3 (L0 pipeline, the recurrence): pollA -> 48 MFMA (Whh0, K=256/wave) ->
//     red0 -> LDS c0a barrier -> cell0 (waves 0-1) -> h0 sc1 store -> vmcnt(0) ->
//     c0b -> tid0 stores flagA. red0 reuse gated by flagA(q+1) itself.
//   Waves 4-7 (L1 pipeline, slack): pollA(q)+pollB(q) -> Wih1*h0[q-1] + Whh1*h1[q-2]
//     (weights STREAMED from L2; 96 MFMA) -> red1 -> c1a -> cell1 (waves 4-5) ->
//     h1 store -> c1b -> flagB. L0 never waits on flagB: 2/3 of the MFMAs and half
//     the loads leave the critical chain. Wave->SIMD round-robin pairs 1 L0 + 1 L1
//     wave per SIMD.
__global__ __launch_bounds__(512, 2)
void lstm_scan2(const u16* __restrict__ W0h, const u16* __restrict__ W0l,
                const u16* __restrict__ WIh, const u16* __restrict__ WIl,
                const u16* __restrict__ W1h, const u16* __restrict__ W1l,
                const float* __restrict__ G0,
                const float* __restrict__ bi1, const float* __restrict__ bh1,
                const u16* __restrict__ s0h, const u16* __restrict__ s0l,
                const u16* __restrict__ s1h, const u16* __restrict__ s1l,
                u16* __restrict__ h0ha, u16* __restrict__ h0la,
                u16* __restrict__ h1ha, u16* __restrict__ h1la,
                u16* __restrict__ hs_h, u16* __restrict__ hs_l,
                const float* __restrict__ c0i, const float* __restrict__ c1i,
                float* __restrict__ c0o, float* __restrict__ c1o,
                unsigned* bar, int pbase, int initfs) {
    __shared__ float red0[4][32][17];
    __shared__ float red1[4][32][17];
    __shared__ unsigned cb4[4];   // 0:c0a 1:c0b 2:c1a 3:c1b
    const int tid = threadIdx.x, lane = tid & 63, wave = tid >> 6, bid = blockIdx.x;
    const int fr = lane & 15, fk = lane >> 4;
    const int fr4 = fr * 4;
    unsigned* flagsA = bar + 16;
    unsigned* flagsB = bar + 16 + 256 * 16;
    if (tid == 0) { cb4[0] = 0; cb4[1] = 0; cb4[2] = 0; cb4[3] = 0; }
    __syncthreads();   // once, pre-loop (counter init)

    if (wave < 4) {
        // ================= L0 pipeline (recurrence-critical) =================
        const size_t woff = (size_t)(bid * 16 + fr) * Hn + wave * 256 + fk * 8;
        DECLW8(w0h_); DECLW8(w0l_);
        LOADW8(w0h_, W0h); LOADW8(w0l_, W0l);
        PINW8(w0h_); PINW8(w0l_);
        const int lt = tid & 127, cbb = lt >> 2, cu = lt & 3, cj = bid * 4 + cu;
        const bool isCell = tid < 128;
        float creg = 0.f;
        if (isCell && initfs) creg = c0i[cbb * Hn + cj];

        for (int q = 0; q < 64; ++q) {
            v4f gq = (v4f){0.f, 0.f, 0.f, 0.f};
            if (isCell)
                gq = *(const v4f*)(G0 + (size_t)bid * ((size_t)MR * 16)
                                   + (size_t)(q * 32 + cbb) * 16 + cu * 4);
            if (q >= 1) poll4(flagsA, (unsigned)(pbase + q), lane);
            const bool hasH0 = (q > 0) || (initfs != 0);
            const u16* h0sh = (q == 0) ? s0h : h0ha + (size_t)(q - 1) * BH;
            const u16* h0sl = (q == 0) ? s0l : h0la + (size_t)(q - 1) * BH;
            v4f r0a = {0,0,0,0}, r0b = {0,0,0,0};
            if (hasH0) {
                KT0L(0) KT0L(1) KT0L(2) KT0L(3) KT0L(4) KT0L(5) KT0L(6) KT0L(7)
            }
#pragma unroll
            for (int pp = 0; pp < 4; ++pp) {
                red0[wave][fk * 4 + pp][fr]      = r0a[pp];
                red0[wave][fk * 4 + pp + 16][fr] = r0b[pp];
            }
            if (lane == 0) lds_arrive(&cb4[0]);
            if (isCell) {
                lds_spin(&cb4[0], 4u * (q + 1));
                float gv[4];
#pragma unroll
                for (int qg = 0; qg < 4; ++qg) {
                    const int rr = qg * 4 + cu;
                    gv[qg] = red0[0][cbb][rr] + red0[1][cbb][rr]
                           + red0[2][cbb][rr] + red0[3][cbb][rr] + gq[qg];
                }
                const float gi = sigm(gv[0]), gf = sigm(gv[1]);
                const float gg = tanh_fast(gv[2]), go = sigm(gv[3]);
                creg = gf * creg + gi * gg;
                const float h = go * tanh_fast(creg);
                u16 hh, hl; split2(h, hh, hl);
                const unsigned prh = (unsigned)(u16)__shfl_xor((int)hh, 1);
                const unsigned prl = (unsigned)(u16)__shfl_xor((int)hl, 1);
                if ((cu & 1) == 0) {
                    const size_t ho2 = (size_t)q * (BH / 2) + bid * 64 + cbb * 2 + (cu >> 1);
                    __hip_atomic_store((unsigned*)h0ha + ho2, (prh << 16) | hh,
                                       __ATOMIC_RELAXED, __HIP_MEMORY_SCOPE_AGENT);
                    __hip_atomic_store((unsigned*)h0la + ho2, (prl << 16) | hl,
                                       __ATOMIC_RELAXED, __HIP_MEMORY_SCOPE_AGENT);
                }
                if (q == 63) {
                    c0o[cbb * Hn + cj] = creg;
                    if (hs_h) {
                        hs_h[bid * 128 + cbb * 4 + cu] = hh;   // block-major seed copy
                        hs_l[bid * 128 + cbb * 4 + cu] = hl;
                    }
                }
                asm volatile("s_waitcnt vmcnt(0)" ::: "memory");   // h0 at LLC
                if (lane == 0) lds_arrive(&cb4[1]);
                if (tid == 0) {
                    lds_spin(&cb4[1], 2u * (q + 1));
                    __hip_atomic_store(&flagsA[bid * 16], (unsigned)(pbase + q + 1),
                                       __ATOMIC_RELAXED, __HIP_MEMORY_SCOPE_AGENT);
                }
            }
        }
    } else {
        // ================= L1 pipeline (slack path) =================
        const int w4 = wave - 4;
        const size_t woffT = (size_t)(bid * 16 + fr) * Hn + w4 * 256 + fk * 8;
        const int lt = (tid - 256) & 127, cbb = lt >> 2, cu = lt & 3, cj = bid * 4 + cu;
        const bool isCell1 = (tid >= 256) && (tid < 384);
        float creg = 0.f;
        float b1v[4] = {0.f, 0.f, 0.f, 0.f};
        if (isCell1) {
            if (initfs) creg = c1i[cbb * Hn + cj];
#pragma unroll
            for (int qg = 0; qg < 4; ++qg) b1v[qg] = bi1[qg * Hn + cj] + bh1[qg * Hn + cj];
        }

        for (int q = 1; q <= 64; ++q) {
            const int t1 = q - 1;
            poll4(flagsA, (unsigned)(pbase + q), lane);           // h0[q-1] visible
            if (q >= 2) poll4(flagsB, (unsigned)(pbase + q), lane);  // h1[q-2] visible
            const bool hasH1 = (q > 1) || (initfs != 0);
            const u16* h0sh = h0ha + (size_t)(q - 1) * BH;
            const u16* h0sl = h0la + (size_t)(q - 1) * BH;
            const u16* h1sh = (q <= 1) ? s1h : h1ha + (size_t)(q - 2) * BH;
            const u16* h1sl = (q <= 1) ? s1l : h1la + (size_t)(q - 2) * BH;
            v4f r1a = {0,0,0,0}, r1b = {0,0,0,0};
            KTIH(0) KTIH(1) KTIH(2) KTIH(3) KTIH(4) KTIH(5) KTIH(6) KTIH(7)
            if (hasH1) {
                KTH1(0) KTH1(1) KTH1(2) KTH1(3) KTH1(4) KTH1(5) KTH1(6) KTH1(7)
            }
#pragma unroll
            for (int pp = 0; pp < 4; ++pp) {
                red1[w4][fk * 4 + pp][fr]      = r1a[pp];
                red1[w4][fk * 4 + pp + 16][fr] = r1b[pp];
            }
            if (lane == 0) lds_arrive(&cb4[2]);
            if (isCell1) {
                lds_spin(&cb4[2], 4u * q);
                float gv[4];
#pragma unroll
                for (int qg = 0; qg < 4; ++qg) {
                    const int rr = qg * 4 + cu;
                    gv[qg] = red1[0][cbb][rr] + red1[1][cbb][rr]
                           + red1[2][cbb][rr] + red1[3][cbb][rr] + b1v[qg];
                }
                const float gi = sigm(gv[0]), gf = sigm(gv[1]);
                const float gg = tanh_fast(gv[2]), go = sigm(gv[3]);
                creg = gf * creg + gi * gg;
                const float h = go * tanh_fast(creg);
                u16 hh, hl; split2(h, hh, hl);
                const unsigned prh = (unsigned)(u16)__shfl_xor((int)hh, 1);
                const unsigned prl = (unsigned)(u16)__shfl_xor((int)hl, 1);
                if ((cu & 1) == 0) {
                    const size_t ho2 = (size_t)t1 * (BH / 2) + bid * 64 + cbb * 2 + (cu >> 1);
                    __hip_atomic_store((unsigned*)h1ha + ho2, (prh << 16) | hh,
                                       __ATOMIC_RELAXED, __HIP_MEMORY_SCOPE_AGENT);
                    __hip_atomic_store((unsigned*)h1la + ho2, (prl << 16) | hl,
                                       __ATOMIC_RELAXED, __HIP_MEMORY_SCOPE_AGENT);
                }
                if (t1 == 63) c1o[cbb * Hn + cj] = creg;
                asm volatile("s_waitcnt vmcnt(0)" ::: "memory");   // h1 at LLC
                if (lane == 0) lds_arrive(&cb4[3]);
                if (tid == 256) {
                    lds_spin(&cb4[3], 2u * q);
                    __hip_atomic_store(&flagsB[bid * 16], (unsigned)(pbase + q + 1),
                                       __ATOMIC_RELAXED, __HIP_MEMORY_SCOPE_AGENT);
                }
            }
        }
    }
}

// ---------------- host launch ----------------
extern "C" void kernel_launch(void* const* d_in, const int* in_sizes, int n_in,
                              void* d_out, int out_size, void* d_ws, size_t ws_size,
                              hipStream_t stream) {
    (void)in_sizes; (void)n_in; (void)out_size; (void)ws_size;
    const int*   input_seq  = (const int*)d_in[0];
    const int*   target_seq = (const int*)d_in[1];
    const float* emb  = (const float*)d_in[2];
    const float* fc_W = (const float*)d_in[3];
    const float* fc_b = (const float*)d_in[4];
    // [0]=enc L0, [1]=enc L1, [2]=dec L0, [3]=dec L1
    const float* W_ih[4] = {(const float*)d_in[5],  (const float*)d_in[9],
                            (const float*)d_in[13], (const float*)d_in[17]};
    const float* W_hh[4] = {(const float*)d_in[6],  (const float*)d_in[10],
                            (const float*)d_in[14], (const float*)d_in[18]};
    const float* b_ih[4] = {(const float*)d_in[7],  (const float*)d_in[11],
                            (const float*)d_in[15], (const float*)d_in[19]};
    const float* b_hh[4] = {(const float*)d_in[8],  (const float*)d_in[12],
                            (const float*)d_in[16], (const float*)d_in[20]};

    char* w = (char*)d_ws;
    size_t off = 0;
    auto alloc = [&](size_t bytes) {
        void* p = (void*)(w + off);
        off += (bytes + 255) & ~(size_t)255;
        return p;
    };
    unsigned* bar = (unsigned*)alloc(BAR_U32 * 4);
    float* G   = (float*)alloc((size_t)MR * FH * 4);     // 33.6 MB, permuted [bid][m][16]
    u16* W0h   = (u16*)alloc((size_t)FH * Hn * 2);       // Whh(L0) perm hi
    u16* W0l   = (u16*)alloc((size_t)FH * Hn * 2);
    u16* WIh   = (u16*)alloc((size_t)FH * Hn * 2);       // Wih(L1) perm hi
    u16* WIl   = (u16*)alloc((size_t)FH * Hn * 2);
    u16* W1h   = (u16*)alloc((size_t)FH * Hn * 2);       // Whh(L1) perm hi
    u16* W1l   = (u16*)alloc((size_t)FH * Hn * 2);
    u16* SWh   = (u16*)alloc((size_t)FH * Hn * 2);       // Wih(L0) split (GEMM B)
    u16* SWl   = (u16*)alloc((size_t)FH * Hn * 2);
    u16* Xh    = (u16*)alloc((size_t)MR * En * 2);       // gathered embeddings hi
    u16* Xl    = (u16*)alloc((size_t)MR * En * 2);
    u16* hAh   = (u16*)alloc((size_t)Tn * BH * 2);       // layer-0 h block-major, hi
    u16* hAl   = (u16*)alloc((size_t)Tn * BH * 2);
    u16* hBh   = (u16*)alloc((size_t)Tn * BH * 2);       // layer-1 h block-major, hi
    u16* hBl   = (u16*)alloc((size_t)Tn * BH * 2);
    u16* hs0h  = (u16*)alloc((size_t)BH * 2);            // enc h0 final seed (block-major)
    u16* hs0l  = (u16*)alloc((size_t)BH * 2);
    float* c0  = (float*)alloc((size_t)BH * 4);          // cell-state carries
    float* c1  = (float*)alloc((size_t)BH * 4);
    u16* hFh   = (u16*)alloc((size_t)MR * Hn * 2);       // dec h1 row-major for FC
    u16* hFl   = (u16*)alloc((size_t)MR * Hn * 2);
    // fc_W bf16 aliases the dead G..WIl region after dec scan (needs 65.5 MB <= 67.2 MB)
    u16* fWh = (u16*)G;

    bar_init<<<1, 256, 0, stream>>>(bar);

    auto scan = [&](const u16* s0hp, const u16* s0lp, const u16* s1hp, const u16* s1lp,
                    u16* hsh, u16* hsl, const float* bi1, const float* bh1,
                    int pbase, int fs) {
        const u16 *a0=W0h,*a1=W0l,*a2=WIh,*a3=WIl,*a4=W1h,*a5=W1l;
        const float* Gp = G;
        u16 *p0=hAh,*p1=hAl,*p2=hBh,*p3=hBl;
        const float *ci0=c0,*ci1=c1; float *co0=c0,*co1=c1;
        unsigned* bp = bar;
        void* args[] = {(void*)&a0,(void*)&a1,(void*)&a2,(void*)&a3,(void*)&a4,(void*)&a5,
                        (void*)&Gp,(void*)&bi1,(void*)&bh1,
                        (void*)&s0hp,(void*)&s0lp,(void*)&s1hp,(void*)&s1lp,
                        (void*)&p0,(void*)&p1,(void*)&p2,(void*)&p3,
                        (void*)&hsh,(void*)&hsl,
                        (void*)&ci0,(void*)&ci1,(void*)&co0,(void*)&co1,
                        (void*)&bp,(void*)&pbase,(void*)&fs};
        if (hipLaunchCooperativeKernel((void*)lstm_scan2, dim3(256), dim3(512),
                                       args, 0, stream) != hipSuccess) {
            // fallback: 256 blocks x 8 waves co-resident on 256 CUs
            lstm_scan2<<<dim3(256), dim3(512), 0, stream>>>(
                W0h, W0l, WIh, WIl, W1h, W1l, G, bi1, bh1,
                s0hp, s0lp, s1hp, s1lp, hAh, hAl, hBh, hBl, hsh, hsl,
                c0, c1, c0, c1, bar, pbase, fs);
        }
    };

    const size_t lastT = (size_t)63 * BH;

    // ---- encoder: G0 = emb(input) @ Wih0^T + biases, then decoupled L0/L1 scan ----
    gather_split<<<MR, 256, 0, stream>>>(emb, input_seq, 0, Xh, Xl);
    split_w<<<2048, 256, 0, stream>>>(W_ih[0], SWh, SWl, FH * En / 4);
    gemm_bt<3, 1><<<dim3(FH / 128, MR / 128), 256, 0, stream>>>(
        Xh, Xl, SWh, SWl, b_ih[0], b_hh[0], G, MR, FH, En);
    perm_split<<<FH, 256, 0, stream>>>(W_hh[0], W0h, W0l);
    perm_split<<<FH, 256, 0, stream>>>(W_ih[1], WIh, WIl);
    perm_split<<<FH, 256, 0, stream>>>(W_hh[1], W1h, W1l);
    scan(hs0h, hs0l, hs0h, hs0l, hs0h, hs0l, b_ih[1], b_hh[1], 0, 0);

    // ---- decoder: teacher forcing inputs = [<sos>, target[:,:-1]] ----
    gather_split<<<MR, 256, 0, stream>>>(emb, target_seq, 1, Xh, Xl);
    split_w<<<2048, 256, 0, stream>>>(W_ih[2], SWh, SWl, FH * En / 4);
    gemm_bt<3, 1><<<dim3(FH / 128, MR / 128), 256, 0, stream>>>(
        Xh, Xl, SWh, SWl, b_ih[2], b_hh[2], G, MR, FH, En);
    perm_split<<<FH, 256, 0, stream>>>(W_hh[2], W0h, W0l);
    perm_split<<<FH, 256, 0, stream>>>(W_ih[3], WIh, WIl);
    perm_split<<<FH, 256, 0, stream>>>(W_hh[3], W1h, W1l);
    // seeds: h0 from fresh copy; h1 from hB[63] (block-major, first touch post-boundary)
    scan(hs0h, hs0l, hBh + lastT, hBl + lastT, nullptr, nullptr,
         b_ih[3], b_hh[3], 70, 1);

    // ---- FC: logits[b][t][v] = dec_h1[t][b][:] . fc_W[v][:] + fc_b[v] ----
    unperm_h<<<MR, 256, 0, stream>>>(hBh, hBl, hFh, hFl);
    split_w<<<2048, 256, 0, stream>>>(fc_W, fWh, nullptr, Vn * Hn / 4);
    gemm_bt<2, 2><<<dim3(Vn / 128, MR / 128), 256, 0, stream>>>(
        hFh, hFl, fWh, nullptr, fc_b, nullptr, (float*)d_out, MR, Vn, Hn);
}

// Round 14
// 1372.584 us; speedup vs baseline: 1.5920x; 1.5920x over previous
//
#include <hip/hip_runtime.h>

#define DEVINL __device__ __forceinline__

typedef unsigned short u16;
typedef __attribute__((ext_vector_type(8))) short v8s;   // 8 x bf16 (as raw i16)
typedef __attribute__((ext_vector_type(4))) short v4s;   // 4 x bf16 (8B)
typedef __attribute__((ext_vector_type(4))) float v4f;

static constexpr int Vn = 32000, En = 512, Hn = 1024, Bn = 32, Tn = 64;
static constexpr int FH = 4096;    // 4*H
static constexpr int MR = 2048;    // S*B == T*B
static constexpr int BH = Bn * Hn; // 32768

// ---------------- numeric helpers ----------------
DEVINL u16 f2bf(float x) {
    unsigned u = __float_as_uint(x);
    return (u16)((u + 0x7FFFu + ((u >> 16) & 1u)) >> 16);   // RNE to bf16
}
DEVINL float bf2f(u16 h) { return __uint_as_float(((unsigned)h) << 16); }
DEVINL void split2(float x, u16 &hi, u16 &lo) {
    u16 h = f2bf(x);
    hi = h;
    lo = f2bf(x - bf2f(h));
}
DEVINL float sigm(float x) { return 1.f / (1.f + __expf(-x)); }
DEVINL float tanh_fast(float x) { return 1.f - 2.f / (__expf(2.f * x) + 1.f); }
DEVINL v4f mf(v8s a, v8s b, v4f c) { return __builtin_amdgcn_mfma_f32_16x16x32_bf16(a, b, c, 0, 0, 0); }
DEVINL v8s cat8(v4s a, v4s b) { return __builtin_shufflevector(a, b, 0, 1, 2, 3, 4, 5, 6, 7); }

// async global->LDS, 16B per lane; LDS dest must be wave-uniform base (+lane*16 implicit)
DEVINL void gload_lds16(const u16* g, u16* l) {
    __builtin_amdgcn_global_load_lds((const __attribute__((address_space(1))) void*)g,
                                     (__attribute__((address_space(3))) void*)l, 16, 0, 0);
}

// ---------------- tiny prep kernels ----------------
// bar layout (u32, 64B-spaced lines): flags [16 + bid*16] (single per-phase flag)
static constexpr int BAR_U32 = 16 + 256 * 16;
__global__ void bar_init(unsigned* bar) {
    for (int i = threadIdx.x; i < BAR_U32; i += 256) bar[i] = 0u;
}

// gather embedding rows for [t*B+b] and split to bf16 hi/lo
__global__ void gather_split(const float* __restrict__ emb, const int* __restrict__ seq,
                             int isdec, u16* __restrict__ xh, u16* __restrict__ xl) {
    const int m = blockIdx.x;          // t*B + b
    const int b = m & 31, t = m >> 5;
    const int id = isdec ? (t == 0 ? 1 : seq[b * 64 + t - 1]) : seq[b * 64 + t];
    const float* src = emb + (size_t)id * En;
    for (int e = threadIdx.x; e < En; e += 256) {
        u16 h, l; split2(src[e], h, l);
        xh[(size_t)m * En + e] = h;
        xl[(size_t)m * En + e] = l;
    }
}

// fp32 -> bf16 hi (+ optional lo), vectorized x4
__global__ void split_w(const float* __restrict__ W, u16* __restrict__ hi,
                        u16* __restrict__ lo, int n4) {
    const int stride = gridDim.x * blockDim.x;
    for (int i = blockIdx.x * blockDim.x + threadIdx.x; i < n4; i += stride) {
        float4 x = ((const float4*)W)[i];
        u16 h0,h1,h2,h3,l0,l1,l2,l3;
        split2(x.x,h0,l0); split2(x.y,h1,l1); split2(x.z,h2,l2); split2(x.w,h3,l3);
        ushort4 hv; hv.x=h0; hv.y=h1; hv.z=h2; hv.w=h3;
        ((ushort4*)hi)[i] = hv;
        if (lo) { ushort4 lv; lv.x=l0; lv.y=l1; lv.z=l2; lv.w=l3; ((ushort4*)lo)[i] = lv; }
    }
}

// W [4096][1024] -> permuted split: dest row (j/4)*16 + q*4 + (j%4)
// scan block bid owns rows [bid*16, bid*16+16) = 4 units x 4 gates, local row = q*4+u
__global__ void perm_split(const float* __restrict__ Whh, u16* __restrict__ ph,
                           u16* __restrict__ pl) {
    const int g = blockIdx.x;                   // global gate row 0..4095
    const int q = g >> 10, j = g & 1023;
    const int dst = (j >> 2) * 16 + q * 4 + (j & 3);
    const int k4 = threadIdx.x;                 // 0..255 -> one float4 (1024/4)
    float4 x = ((const float4*)(Whh + (size_t)g * Hn))[k4];
    u16 h0,h1,h2,h3,l0,l1,l2,l3;
    split2(x.x,h0,l0); split2(x.y,h1,l1); split2(x.z,h2,l2); split2(x.w,h3,l3);
    ushort4 hv; hv.x=h0; hv.y=h1; hv.z=h2; hv.w=h3;
    ushort4 lv; lv.x=l0; lv.y=l1; lv.z=l2; lv.w=l3;
    ((ushort4*)(ph + (size_t)dst * Hn))[k4] = hv;
    ((ushort4*)(pl + (size_t)dst * Hn))[k4] = lv;
}

// block-major h [t][bid][cb][cu] -> row-major [m=t*32+b][k] for the FC GEMM
__global__ void unperm_h(const u16* __restrict__ ph, const u16* __restrict__ pl,
                         u16* __restrict__ oh, u16* __restrict__ ol) {
    const int m = blockIdx.x, t = m >> 5, b = m & 31;
    const int e = threadIdx.x;   // bid = e (1024/4 = 256 bids)
    const size_t src = (size_t)t * BH + (size_t)e * 128 + b * 4;
    const size_t dst = (size_t)m * Hn + (size_t)e * 4;
    *(v4s*)(oh + dst) = *(const v4s*)(ph + src);
    *(v4s*)(ol + dst) = *(const v4s*)(pl + src);
}

// ---------------- split-bf16 MFMA GEMM: C[M][N] = A[M][K] * B[N][K]^T + bias ----------------
// TERMS: 1 = Ahi*Bhi ; 2 = + Alo*Bhi ; 3 = + Ahi*Blo
// MODE:  0 = row-major C ; 1 = G-permute [bid][m][16] (r = u*4+q) ; 2 = FC remap [b][t][v]
// staging via global_load_lds width=16 (m97 lever) + bijective XCD blockIdx swizzle.
template<int TERMS, int MODE>
__global__ __launch_bounds__(256)
void gemm_bt(const u16* __restrict__ Ahi, const u16* __restrict__ Alo,
             const u16* __restrict__ Bhi, const u16* __restrict__ Blo,
             const float* __restrict__ bias1, const float* __restrict__ bias2,
             float* __restrict__ Cout, int M, int N, int K) {
    constexpr bool AL = (TERMS >= 2), BL = (TERMS >= 3);
    __shared__ __align__(16) u16 sAh[128 * 32];
    __shared__ __align__(16) u16 sBh[128 * 32];
    __shared__ __align__(16) u16 sAl[AL ? 128 * 32 : 8];
    __shared__ __align__(16) u16 sBl[BL ? 128 * 32 : 8];

    const int tid = threadIdx.x;
    const int lane = tid & 63, wave = tid >> 6;
    const int wr = wave >> 1, wc = wave & 1;
    // bijective XCD swizzle (nwg % 8 == 0 for all our grids)
    const int nwgx = gridDim.x;
    const int nwg = nwgx * gridDim.y;
    int wg = blockIdx.y * nwgx + blockIdx.x;
    wg = (wg & 7) * (nwg >> 3) + (wg >> 3);
    const int m0 = (wg / nwgx) * 128, n0 = (wg % nwgx) * 128;
    const int fr = lane & 15, fk = lane >> 4;

    v4f acc[4][4];
#pragma unroll
    for (int i = 0; i < 4; ++i)
#pragma unroll
        for (int j = 0; j < 4; ++j) acc[i][j] = (v4f){0.f, 0.f, 0.f, 0.f};

    // staging: 512 chunks of 16B per matrix; chunk c -> LDS byte c*16 (linear),
    // so the wave-uniform-dest constraint of global_load_lds is met exactly.
    const int c0 = tid, c1 = tid + 256;
    const int r0 = c0 >> 2, kg0 = c0 & 3, r1 = c1 >> 2, kg1 = c1 & 3;
    const int cw0 = (tid & ~63) * 8;          // wave-uniform LDS elem base, half 0
    const int cw1 = cw0 + 256 * 8;            // half 1

    for (int kk = 0; kk < K; kk += 32) {
        const size_t a0 = (size_t)(m0 + r0) * K + kk + kg0 * 8;
        const size_t a1 = (size_t)(m0 + r1) * K + kk + kg1 * 8;
        const size_t b0 = (size_t)(n0 + r0) * K + kk + kg0 * 8;
        const size_t b1 = (size_t)(n0 + r1) * K + kk + kg1 * 8;
        gload_lds16(Ahi + a0, sAh + cw0);
        gload_lds16(Ahi + a1, sAh + cw1);
        gload_lds16(Bhi + b0, sBh + cw0);
        gload_lds16(Bhi + b1, sBh + cw1);
        if constexpr (AL) {
            gload_lds16(Alo + a0, sAl + cw0);
            gload_lds16(Alo + a1, sAl + cw1);
        }
        if constexpr (BL) {
            gload_lds16(Blo + b0, sBl + cw0);
            gload_lds16(Blo + b1, sBl + cw1);
        }
        __syncthreads();   // drains vmcnt: all global_load_lds landed

        v8s ah[4], bh[4], al[4], bl[4];
#pragma unroll
        for (int mt = 0; mt < 4; ++mt) {
            const int row = wr * 64 + mt * 16 + fr;
            const int idx = row * 32 + fk * 8;
            ah[mt] = *(const v8s*)(sAh + idx);
            if constexpr (AL) al[mt] = *(const v8s*)(sAl + idx);
        }
#pragma unroll
        for (int nt = 0; nt < 4; ++nt) {
            const int row = wc * 64 + nt * 16 + fr;
            const int idx = row * 32 + fk * 8;
            bh[nt] = *(const v8s*)(sBh + idx);
            if constexpr (BL) bl[nt] = *(const v8s*)(sBl + idx);
        }
#pragma unroll
        for (int mt = 0; mt < 4; ++mt)
#pragma unroll
            for (int nt = 0; nt < 4; ++nt) {
                acc[mt][nt] = mf(ah[mt], bh[nt], acc[mt][nt]);
                if constexpr (AL) acc[mt][nt] = mf(al[mt], bh[nt], acc[mt][nt]);
                if constexpr (BL) acc[mt][nt] = mf(ah[mt], bl[nt], acc[mt][nt]);
            }
        __syncthreads();
    }

    // epilogue: D layout col = lane&15, row = (lane>>4)*4 + p  [m89-verified]
#pragma unroll
    for (int nt = 0; nt < 4; ++nt) {
        const int col = n0 + wc * 64 + nt * 16 + fr;
        float bsum = bias1 ? bias1[col] : 0.f;
        if (bias2) bsum += bias2[col];
#pragma unroll
        for (int mt = 0; mt < 4; ++mt) {
            const int rowb = m0 + wr * 64 + mt * 16 + fk * 4;
#pragma unroll
            for (int p = 0; p < 4; ++p) {
                const int row = rowb + p;
                const float v = acc[mt][nt][p] + bsum;
                if constexpr (MODE == 2) {
                    const int t = row >> 5, b = row & 31;
                    Cout[(size_t)b * ((size_t)Tn * Vn) + (size_t)t * Vn + col] = v;
                } else if constexpr (MODE == 1) {
                    const int q = col >> 10, j = col & 1023;
                    const int bidw = j >> 2, rloc = (j & 3) * 4 + q;
                    Cout[(size_t)bidw * ((size_t)MR * 16) + (size_t)row * 16 + rloc] = v;
                } else {
                    Cout[(size_t)row * N + col] = v;
                }
            }
        }
    }
}

// ---------------- one-hop single-flag barrier (512-thr blocks: first 256 poll) -------
// Single flag: ONE wait (covers h0[p-1] AND h1[p-2], both stored before flag p) +
// ONE signal per phase. Visibility chain (validated R6-R12): h stored via sc1
// write-through atomics; per-wave vmcnt(0) drain before s_barrier => after signal's
// entry __syncthreads all h is LLC-visible; flag is a relaxed agent store. Readers:
// phase-unique addresses -> no stale local lines. No wbl2 anywhere in the loop.
DEVINL void wait_flags(unsigned* flags, unsigned tgt) {
    if (threadIdx.x < 256) {
        while (__hip_atomic_load(&flags[threadIdx.x * 16], __ATOMIC_RELAXED, __HIP_MEMORY_SCOPE_AGENT) < tgt)
            __builtin_amdgcn_s_sleep(1);
    }
    __syncthreads();
}
DEVINL void signal_phase(unsigned* flags, unsigned val) {
    __syncthreads();   // drains vmcnt(0): sc1 h-stores visible chip-wide
    if (threadIdx.x == 0)
        __hip_atomic_store(&flags[blockIdx.x * 16], val, __ATOMIC_RELAXED, __HIP_MEMORY_SCOPE_AGENT);
}

// ---- named-register weight pinning (4 KT subtiles per wave, K=128/wave; 96 VGPRs).
// asm "+v" makes each fragment an asm output -> reload from memory is illegal
// (gfx950 unified RF: allocator parks them in AGPRs, invisible to VGPR_Count).
// R13 lesson: pinning is load-bearing — streaming ANY weight matrix thrashes L2
// (128KB/block/phase x 32 blocks/XCD = full L2) and regressed 2x.
#define DECLW(P) v8s P##0, P##1, P##2, P##3
#define LOADW(P, BASE) do { const u16* _b = (BASE) + woff; \
    P##0 = *(const v8s*)(_b);       P##1 = *(const v8s*)(_b + 32); \
    P##2 = *(const v8s*)(_b + 64);  P##3 = *(const v8s*)(_b + 96); } while (0)
#define PINW(P) asm volatile("" : "+v"(P##0), "+v"(P##1), "+v"(P##2), "+v"(P##3))

// ---- block-major h fragment load: h stored [t][bid][cb 0..31][cu 0..3].
// For k-subtile kt, lane (fr,fk) needs k = wave*128 + kt*32 + fk*8 + e (e=0..7)
// -> bids {b0, b0+1} with b0 = wave*32 + kt*8 + fk*2; element (cb,k) lives at
// bid*128 + cb*4 + (k&3). Two 8B loads per fragment; coalesced.
#define LD8(B, B0, RO) cat8(*(const v4s*)((B) + (size_t)(B0) * 128 + (RO)), \
                            *(const v4s*)((B) + (size_t)(B0) * 128 + 128 + (RO)))

// one K-subtile (32 elems) of the h0-driven MFMAs: L0 (Whh0) + L1 input (Wih1)
#define KT0(K) { \
    const int b0 = wave * 32 + K * 8 + fk * 2; \
    v8s hah = LD8(h0sh, b0, fr4); \
    v8s hal = LD8(h0sl, b0, fr4); \
    v8s hbh = LD8(h0sh, b0, fr4 + 64); \
    v8s hbl = LD8(h0sl, b0, fr4 + 64); \
    if (doL0) { \
        r0a = mf(hah, w0h_##K, r0a); r0a = mf(hal, w0h_##K, r0a); r0a = mf(hah, w0l_##K, r0a); \
        r0b = mf(hbh, w0h_##K, r0b); r0b = mf(hbl, w0h_##K, r0b); r0b = mf(hbh, w0l_##K, r0b); } \
    if (doL1) { \
        r1a = mf(hah, wih_##K, r1a); r1a = mf(hal, wih_##K, r1a); r1a = mf(hah, wil_##K, r1a); \
        r1b = mf(hbh, wih_##K, r1b); r1b = mf(hbl, wih_##K, r1b); r1b = mf(hbh, wil_##K, r1b); } }

// one K-subtile of the h1-driven MFMAs: L1 recurrent (Whh1)
#define KT1(K) { \
    const int b0 = wave * 32 + K * 8 + fk * 2; \
    v8s hah = LD8(h1sh, b0, fr4); \
    v8s hal = LD8(h1sl, b0, fr4); \
    v8s hbh = LD8(h1sh, b0, fr4 + 64); \
    v8s hbl = LD8(h1sl, b0, fr4 + 64); \
    r1a = mf(hah, w1h_##K, r1a); r1a = mf(hal, w1h_##K, r1a); r1a = mf(hah, w1l_##K, r1a); \
    r1b = mf(hbh, w1h_##K, r1b); r1b = mf(hbl, w1h_##K, r1b); r1b = mf(hbh, w1l_##K, r1b); }

// ---------------- merged 2-layer LSTM scan: single-flag merged phase (R12, best) ----------
// Phase p: L0 computes t0=p (p<64), L1 computes t1=p-1 (p>=1); both consume h0[p-1],
// L1 also h1[p-2]. ONE wait at phase top covers both (flag p = phase p-1 fully done).
// KT0+KT1 loads/MFMAs issue as one stream (compiler pipelines); ONE red sync; cells
// for L0 (tid<128) and L1 (tid 128-255) run CONCURRENTLY; ONE signal.
__global__ __launch_bounds__(512, 2)
void lstm_scan2(const u16* __restrict__ W0h, const u16* __restrict__ W0l,
                const u16* __restrict__ WIh, const u16* __restrict__ WIl,
                const u16* __restrict__ W1h, const u16* __restrict__ W1l,
                const float* __restrict__ G0,
                const float* __restrict__ bi1, const float* __restrict__ bh1,
                const u16* __restrict__ s0h, const u16* __restrict__ s0l,
                const u16* __restrict__ s1h, const u16* __restrict__ s1l,
                u16* __restrict__ h0ha, u16* __restrict__ h0la,
                u16* __restrict__ h1ha, u16* __restrict__ h1la,
                u16* __restrict__ hs_h, u16* __restrict__ hs_l,
                const float* __restrict__ c0i, const float* __restrict__ c1i,
                float* __restrict__ c0o, float* __restrict__ c1o,
                unsigned* bar, int pbase, int initfs) {
    __shared__ float red0[8][32][17];
    __shared__ float red1[8][32][17];
    const int tid = threadIdx.x, lane = tid & 63, wave = tid >> 6, bid = blockIdx.x;
    const int fr = lane & 15, fk = lane >> 4;
    const int fr4 = fr * 4;
    const size_t woff = (size_t)(bid * 16 + fr) * Hn + wave * 128 + fk * 8;
    unsigned* flags = bar + 16;

    DECLW(w0h_); DECLW(w0l_); DECLW(wih_); DECLW(wil_); DECLW(w1h_); DECLW(w1l_);
    LOADW(w0h_, W0h); LOADW(w0l_, W0l);
    LOADW(wih_, WIh); LOADW(wil_, WIl);
    LOADW(w1h_, W1h); LOADW(w1l_, W1l);
    PINW(w0h_); PINW(w0l_); PINW(wih_); PINW(wil_); PINW(w1h_); PINW(w1l_);

    const int lt = tid & 127, cb = lt >> 2, cu = lt & 3, cj = bid * 4 + cu;
    const bool isL0 = tid < 128;
    const bool isL1 = (tid >= 128) && (tid < 256);
    float creg = 0.f;
    float b1v[4];
    if (isL0) {
        if (initfs) creg = c0i[cb * Hn + cj];
    } else if (isL1) {
        if (initfs) creg = c1i[cb * Hn + cj];
#pragma unroll
        for (int q = 0; q < 4; ++q) b1v[q] = bi1[q * Hn + cj] + bh1[q * Hn + cj];
    }

    for (int p = 0; p <= 64; ++p) {
        const bool doL0 = (p < 64), doL1 = (p >= 1);
        const bool hasH0 = (p > 0) || (initfs != 0);
        const bool hasH1 = doL1 && ((p > 1) || (initfs != 0));
        const u16* h0sh = (p == 0) ? s0h : h0ha + (size_t)(p - 1) * BH;
        const u16* h0sl = (p == 0) ? s0l : h0la + (size_t)(p - 1) * BH;
        const u16* h1sh = (p <= 1) ? s1h : h1ha + (size_t)(p - 2) * BH;
        const u16* h1sl = (p <= 1) ? s1l : h1la + (size_t)(p - 2) * BH;

        // issue G prefetch BEFORE the wait poll (HBM latency hides under detection)
        v4f gq = (v4f){0.f, 0.f, 0.f, 0.f};
        if (isL0 && doL0)
            gq = *(const v4f*)(G0 + (size_t)bid * ((size_t)MR * 16)
                               + (size_t)(p * 32 + cb) * 16 + cu * 4);

        if (p >= 1) wait_flags(flags, (unsigned)(pbase + p));   // h0[p-1] AND h1[p-2] visible

        v4f r0a = {0,0,0,0}, r0b = {0,0,0,0}, r1a = {0,0,0,0}, r1b = {0,0,0,0};
        if (hasH0) {
            KT0(0) KT0(1) KT0(2) KT0(3)
        }
        if (hasH1) {
            KT1(0) KT1(1) KT1(2) KT1(3)
        }
        if (doL0 && hasH0) {
#pragma unroll
            for (int pp = 0; pp < 4; ++pp) {
                red0[wave][fk * 4 + pp][fr]      = r0a[pp];
                red0[wave][fk * 4 + pp + 16][fr] = r0b[pp];
            }
        }
        if (doL1) {
#pragma unroll
            for (int pp = 0; pp < 4; ++pp) {
                red1[wave][fk * 4 + pp][fr]      = r1a[pp];
                red1[wave][fk * 4 + pp + 16][fr] = r1b[pp];
            }
        }
        __syncthreads();   // red0 + red1 ready

        if (isL0) {
            if (doL0) {
                float gv[4];
#pragma unroll
                for (int q = 0; q < 4; ++q) {
                    const int rr = q * 4 + cu;
                    float s = 0.f;
                    if (hasH0) {
#pragma unroll
                        for (int wv = 0; wv < 8; ++wv) s += red0[wv][cb][rr];
                    }
                    gv[q] = s + gq[q];
                }
                const float gi = sigm(gv[0]), gf = sigm(gv[1]);
                const float gg = tanh_fast(gv[2]), go = sigm(gv[3]);
                creg = gf * creg + gi * gg;
                const float h = go * tanh_fast(creg);
                u16 hh, hl; split2(h, hh, hl);
                // pack unit-pairs via shfl; even-cu lane stores u32 write-through (sc1).
                // Block-major layout: u32 idx = bid*64 + cb*2 + cu/2 (256B contiguous/block)
                const unsigned prh = (unsigned)(u16)__shfl_xor((int)hh, 1);
                const unsigned prl = (unsigned)(u16)__shfl_xor((int)hl, 1);
                if ((cu & 1) == 0) {
                    const size_t ho2 = (size_t)p * (BH / 2) + bid * 64 + cb * 2 + (cu >> 1);
                    __hip_atomic_store((unsigned*)h0ha + ho2, (prh << 16) | hh,
                                       __ATOMIC_RELAXED, __HIP_MEMORY_SCOPE_AGENT);
                    __hip_atomic_store((unsigned*)h0la + ho2, (prl << 16) | hl,
                                       __ATOMIC_RELAXED, __HIP_MEMORY_SCOPE_AGENT);
                }
                if (p == 63) {
                    c0o[cb * Hn + cj] = creg;            // cross-kernel: end-of-kernel flush
                    if (hs_h) {
                        hs_h[bid * 128 + cb * 4 + cu] = hh;   // block-major seed copy
                        hs_l[bid * 128 + cb * 4 + cu] = hl;
                    }
                }
            }
        } else if (isL1) {
            if (doL1) {
                const int t1 = p - 1;
                float gv[4];
#pragma unroll
                for (int q = 0; q < 4; ++q) {
                    const int rr = q * 4 + cu;
                    float s = b1v[q];
#pragma unroll
                    for (int wv = 0; wv < 8; ++wv) s += red1[wv][cb][rr];
                    gv[q] = s;
                }
                const float gi = sigm(gv[0]), gf = sigm(gv[1]);
                const float gg = tanh_fast(gv[2]), go = sigm(gv[3]);
                creg = gf * creg + gi * gg;
                const float h = go * tanh_fast(creg);
                u16 hh, hl; split2(h, hh, hl);
                const unsigned prh = (unsigned)(u16)__shfl_xor((int)hh, 1);
                const unsigned prl = (unsigned)(u16)__shfl_xor((int)hl, 1);
                if ((cu & 1) == 0) {
                    const size_t ho2 = (size_t)t1 * (BH / 2) + bid * 64 + cb * 2 + (cu >> 1);
                    __hip_atomic_store((unsigned*)h1ha + ho2, (prh << 16) | hh,
                                       __ATOMIC_RELAXED, __HIP_MEMORY_SCOPE_AGENT);
                    __hip_atomic_store((unsigned*)h1la + ho2, (prl << 16) | hl,
                                       __ATOMIC_RELAXED, __HIP_MEMORY_SCOPE_AGENT);
                }
                if (t1 == 63) c1o[cb * Hn + cj] = creg;  // cross-kernel: end-of-kernel flush
            }
        }
        signal_phase(flags, (unsigned)(pbase + p + 1));
    }
}

// ---------------- host launch ----------------
extern "C" void kernel_launch(void* const* d_in, const int* in_sizes, int n_in,
                              void* d_out, int out_size, void* d_ws, size_t ws_size,
                              hipStream_t stream) {
    (void)in_sizes; (void)n_in; (void)out_size; (void)ws_size;
    const int*   input_seq  = (const int*)d_in[0];
    const int*   target_seq = (const int*)d_in[1];
    const float* emb  = (const float*)d_in[2];
    const float* fc_W = (const float*)d_in[3];
    const float* fc_b = (const float*)d_in[4];
    // [0]=enc L0, [1]=enc L1, [2]=dec L0, [3]=dec L1
    const float* W_ih[4] = {(const float*)d_in[5],  (const float*)d_in[9],
                            (const float*)d_in[13], (const float*)d_in[17]};
    const float* W_hh[4] = {(const float*)d_in[6],  (const float*)d_in[10],
                            (const float*)d_in[14], (const float*)d_in[18]};
    const float* b_ih[4] = {(const float*)d_in[7],  (const float*)d_in[11],
                            (const float*)d_in[15], (const float*)d_in[19]};
    const float* b_hh[4] = {(const float*)d_in[8],  (const float*)d_in[12],
                            (const float*)d_in[16], (const float*)d_in[20]};

    char* w = (char*)d_ws;
    size_t off = 0;
    auto alloc = [&](size_t bytes) {
        void* p = (void*)(w + off);
        off += (bytes + 255) & ~(size_t)255;
        return p;
    };
    unsigned* bar = (unsigned*)alloc(BAR_U32 * 4);
    float* G   = (float*)alloc((size_t)MR * FH * 4);     // 33.6 MB, permuted [bid][m][16]
    u16* W0h   = (u16*)alloc((size_t)FH * Hn * 2);       // Whh(L0) perm hi
    u16* W0l   = (u16*)alloc((size_t)FH * Hn * 2);
    u16* WIh   = (u16*)alloc((size_t)FH * Hn * 2);       // Wih(L1) perm hi
    u16* WIl   = (u16*)alloc((size_t)FH * Hn * 2);
    u16* W1h   = (u16*)alloc((size_t)FH * Hn * 2);       // Whh(L1) perm hi
    u16* W1l   = (u16*)alloc((size_t)FH * Hn * 2);
    u16* SWh   = (u16*)alloc((size_t)FH * Hn * 2);       // Wih(L0) split (GEMM B)
    u16* SWl   = (u16*)alloc((size_t)FH * Hn * 2);
    u16* Xh    = (u16*)alloc((size_t)MR * En * 2);       // gathered embeddings hi
    u16* Xl    = (u16*)alloc((size_t)MR * En * 2);
    u16* hAh   = (u16*)alloc((size_t)Tn * BH * 2);       // layer-0 h block-major, hi
    u16* hAl   = (u16*)alloc((size_t)Tn * BH * 2);
    u16* hBh   = (u16*)alloc((size_t)Tn * BH * 2);       // layer-1 h block-major, hi
    u16* hBl   = (u16*)alloc((size_t)Tn * BH * 2);
    u16* hs0h  = (u16*)alloc((size_t)BH * 2);            // enc h0 final seed (block-major)
    u16* hs0l  = (u16*)alloc((size_t)BH * 2);
    float* c0  = (float*)alloc((size_t)BH * 4);          // cell-state carries
    float* c1  = (float*)alloc((size_t)BH * 4);
    u16* hFh   = (u16*)alloc((size_t)MR * Hn * 2);       // dec h1 row-major for FC
    u16* hFl   = (u16*)alloc((size_t)MR * Hn * 2);
    // fc_W bf16 aliases the dead G..WIl region after dec scan (needs 65.5 MB <= 67.2 MB)
    u16* fWh = (u16*)G;

    bar_init<<<1, 256, 0, stream>>>(bar);

    auto scan = [&](const u16* s0hp, const u16* s0lp, const u16* s1hp, const u16* s1lp,
                    u16* hsh, u16* hsl, const float* bi1, const float* bh1,
                    int pbase, int fs) {
        const u16 *a0=W0h,*a1=W0l,*a2=WIh,*a3=WIl,*a4=W1h,*a5=W1l;
        const float* Gp = G;
        u16 *p0=hAh,*p1=hAl,*p2=hBh,*p3=hBl;
        const float *ci0=c0,*ci1=c1; float *co0=c0,*co1=c1;
        unsigned* bp = bar;
        void* args[] = {(void*)&a0,(void*)&a1,(void*)&a2,(void*)&a3,(void*)&a4,(void*)&a5,
                        (void*)&Gp,(void*)&bi1,(void*)&bh1,
                        (void*)&s0hp,(void*)&s0lp,(void*)&s1hp,(void*)&s1lp,
                        (void*)&p0,(void*)&p1,(void*)&p2,(void*)&p3,
                        (void*)&hsh,(void*)&hsl,
                        (void*)&ci0,(void*)&ci1,(void*)&co0,(void*)&co1,
                        (void*)&bp,(void*)&pbase,(void*)&fs};
        if (hipLaunchCooperativeKernel((void*)lstm_scan2, dim3(256), dim3(512),
                                       args, 0, stream) != hipSuccess) {
            // fallback: 256 blocks x 8 waves co-resident on 256 CUs
            lstm_scan2<<<dim3(256), dim3(512), 0, stream>>>(
                W0h, W0l, WIh, WIl, W1h, W1l, G, bi1, bh1,
                s0hp, s0lp, s1hp, s1lp, hAh, hAl, hBh, hBl, hsh, hsl,
                c0, c1, c0, c1, bar, pbase, fs);
        }
    };

    const size_t lastT = (size_t)63 * BH;

    // ---- encoder: G0 = emb(input) @ Wih0^T + biases, then merged L0+L1 scan ----
    gather_split<<<MR, 256, 0, stream>>>(emb, input_seq, 0, Xh, Xl);
    split_w<<<2048, 256, 0, stream>>>(W_ih[0], SWh, SWl, FH * En / 4);
    gemm_bt<3, 1><<<dim3(FH / 128, MR / 128), 256, 0, stream>>>(
        Xh, Xl, SWh, SWl, b_ih[0], b_hh[0], G, MR, FH, En);
    perm_split<<<FH, 256, 0, stream>>>(W_hh[0], W0h, W0l);
    perm_split<<<FH, 256, 0, stream>>>(W_ih[1], WIh, WIl);
    perm_split<<<FH, 256, 0, stream>>>(W_hh[1], W1h, W1l);
    scan(hs0h, hs0l, hs0h, hs0l, hs0h, hs0l, b_ih[1], b_hh[1], 0, 0);

    // ---- decoder: teacher forcing inputs = [<sos>, target[:,:-1]] ----
    gather_split<<<MR, 256, 0, stream>>>(emb, target_seq, 1, Xh, Xl);
    split_w<<<2048, 256, 0, stream>>>(W_ih[2], SWh, SWl, FH * En / 4);
    gemm_bt<3, 1><<<dim3(FH / 128, MR / 128), 256, 0, stream>>>(
        Xh, Xl, SWh, SWl, b_ih[2], b_hh[2], G, MR, FH, En);
    perm_split<<<FH, 256, 0, stream>>>(W_hh[2], W0h, W0l);
    perm_split<<<FH, 256, 0, stream>>>(W_ih[3], WIh, WIl);
    perm_split<<<FH, 256, 0, stream>>>(W_hh[3], W1h, W1l);
    // seeds: h0 from fresh copy; h1 from hB[63] (block-major, first touch post-boundary)
    scan(hs0h, hs0l, hBh + lastT, hBl + lastT, nullptr, nullptr,
         b_ih[3], b_hh[3], 65, 1);

    // ---- FC: logits[b][t][v] = dec_h1[t][b][:] . fc_W[v][:] + fc_b[v] ----
    unperm_h<<<MR, 256, 0, stream>>>(hBh, hBl, hFh, hFl);
    split_w<<<2048, 256, 0, stream>>>(fc_W, fWh, nullptr, Vn * Hn / 4);
    gemm_bt<2, 2><<<dim3(Vn / 128, MR / 128), 256, 0, stream>>>(
        hFh, hFl, fWh, nullptr, fc_b, nullptr, (float*)d_out, MR, Vn, Hn);
}

// Round 15
// 1357.710 us; speedup vs baseline: 1.6094x; 1.0110x over previous
//
#include <hip/hip_runtime.h>

#define DEVINL __device__ __forceinline__

typedef unsigned short u16;
typedef __attribute__((ext_vector_type(8))) short v8s;   // 8 x bf16 (as raw i16)
typedef __attribute__((ext_vector_type(4))) short v4s;   // 4 x bf16 (8B)
typedef __attribute__((ext_vector_type(4))) float v4f;

static constexpr int Vn = 32000, En = 512, Hn = 1024, Bn = 32, Tn = 64;
static constexpr int FH = 4096;    // 4*H
static constexpr int MR = 2048;    // S*B == T*B
static constexpr int BH = Bn * Hn; // 32768

// ---------------- numeric helpers ----------------
DEVINL u16 f2bf(float x) {
    unsigned u = __float_as_uint(x);
    return (u16)((u + 0x7FFFu + ((u >> 16) & 1u)) >> 16);   // RNE to bf16
}
DEVINL float bf2f(u16 h) { return __uint_as_float(((unsigned)h) << 16); }
DEVINL void split2(float x, u16 &hi, u16 &lo) {
    u16 h = f2bf(x);
    hi = h;
    lo = f2bf(x - bf2f(h));
}
DEVINL float sigm(float x) { return 1.f / (1.f + __expf(-x)); }
DEVINL float tanh_fast(float x) { return 1.f - 2.f / (__expf(2.f * x) + 1.f); }
DEVINL v4f mf(v8s a, v8s b, v4f c) { return __builtin_amdgcn_mfma_f32_16x16x32_bf16(a, b, c, 0, 0, 0); }
DEVINL v8s cat8(v4s a, v4s b) { return __builtin_shufflevector(a, b, 0, 1, 2, 3, 4, 5, 6, 7); }

// async global->LDS, 16B per lane; LDS dest must be wave-uniform base (+lane*16 implicit)
DEVINL void gload_lds16(const u16* g, u16* l) {
    __builtin_amdgcn_global_load_lds((const __attribute__((address_space(1))) void*)g,
                                     (__attribute__((address_space(3))) void*)l, 16, 0, 0);
}

// ---------------- tiny prep kernels ----------------
// bar layout (u32, 64B-spaced lines): flags [16 + bid*16] (single per-phase flag)
static constexpr int BAR_U32 = 16 + 256 * 16;
__global__ void bar_init(unsigned* bar) {
    for (int i = threadIdx.x; i < BAR_U32; i += 256) bar[i] = 0u;
}

// gather embedding rows for [t*B+b] and split to bf16 hi/lo
__global__ void gather_split(const float* __restrict__ emb, const int* __restrict__ seq,
                             int isdec, u16* __restrict__ xh, u16* __restrict__ xl) {
    const int m = blockIdx.x;          // t*B + b
    const int b = m & 31, t = m >> 5;
    const int id = isdec ? (t == 0 ? 1 : seq[b * 64 + t - 1]) : seq[b * 64 + t];
    const float* src = emb + (size_t)id * En;
    for (int e = threadIdx.x; e < En; e += 256) {
        u16 h, l; split2(src[e], h, l);
        xh[(size_t)m * En + e] = h;
        xl[(size_t)m * En + e] = l;
    }
}

// fp32 -> bf16 hi (+ optional lo), vectorized x4
__global__ void split_w(const float* __restrict__ W, u16* __restrict__ hi,
                        u16* __restrict__ lo, int n4) {
    const int stride = gridDim.x * blockDim.x;
    for (int i = blockIdx.x * blockDim.x + threadIdx.x; i < n4; i += stride) {
        float4 x = ((const float4*)W)[i];
        u16 h0,h1,h2,h3,l0,l1,l2,l3;
        split2(x.x,h0,l0); split2(x.y,h1,l1); split2(x.z,h2,l2); split2(x.w,h3,l3);
        ushort4 hv; hv.x=h0; hv.y=h1; hv.z=h2; hv.w=h3;
        ((ushort4*)hi)[i] = hv;
        if (lo) { ushort4 lv; lv.x=l0; lv.y=l1; lv.z=l2; lv.w=l3; ((ushort4*)lo)[i] = lv; }
    }
}

// W [4096][1024] -> permuted split: dest row (j/4)*16 + q*4 + (j%4)
// scan block bid owns rows [bid*16, bid*16+16) = 4 units x 4 gates, local row = q*4+u
__global__ void perm_split(const float* __restrict__ Whh, u16* __restrict__ ph,
                           u16* __restrict__ pl) {
    const int g = blockIdx.x;                   // global gate row 0..4095
    const int q = g >> 10, j = g & 1023;
    const int dst = (j >> 2) * 16 + q * 4 + (j & 3);
    const int k4 = threadIdx.x;                 // 0..255 -> one float4 (1024/4)
    float4 x = ((const float4*)(Whh + (size_t)g * Hn))[k4];
    u16 h0,h1,h2,h3,l0,l1,l2,l3;
    split2(x.x,h0,l0); split2(x.y,h1,l1); split2(x.z,h2,l2); split2(x.w,h3,l3);
    ushort4 hv; hv.x=h0; hv.y=h1; hv.z=h2; hv.w=h3;
    ushort4 lv; lv.x=l0; lv.y=l1; lv.z=l2; lv.w=l3;
    ((ushort4*)(ph + (size_t)dst * Hn))[k4] = hv;
    ((ushort4*)(pl + (size_t)dst * Hn))[k4] = lv;
}

// block-major h [t][bid][cb][cu] -> row-major [m=t*32+b][k] for the FC GEMM
__global__ void unperm_h(const u16* __restrict__ ph, const u16* __restrict__ pl,
                         u16* __restrict__ oh, u16* __restrict__ ol) {
    const int m = blockIdx.x, t = m >> 5, b = m & 31;
    const int e = threadIdx.x;   // bid = e (1024/4 = 256 bids)
    const size_t src = (size_t)t * BH + (size_t)e * 128 + b * 4;
    const size_t dst = (size_t)m * Hn + (size_t)e * 4;
    *(v4s*)(oh + dst) = *(const v4s*)(ph + src);
    *(v4s*)(ol + dst) = *(const v4s*)(pl + src);
}

// ---------------- split-bf16 MFMA GEMM: C[M][N] = A[M][K] * B[N][K]^T + bias ----------------
// TERMS: 1 = Ahi*Bhi ; 2 = + Alo*Bhi ; 3 = + Ahi*Blo
// MODE:  0 = row-major C ; 1 = G-permute [bid][m][16] (r = u*4+q) ; 2 = FC remap [b][t][v]
// staging via global_load_lds width=16 (m97 lever) + bijective XCD blockIdx swizzle.
template<int TERMS, int MODE>
__global__ __launch_bounds__(256)
void gemm_bt(const u16* __restrict__ Ahi, const u16* __restrict__ Alo,
             const u16* __restrict__ Bhi, const u16* __restrict__ Blo,
             const float* __restrict__ bias1, const float* __restrict__ bias2,
             float* __restrict__ Cout, int M, int N, int K) {
    constexpr bool AL = (TERMS >= 2), BL = (TERMS >= 3);
    __shared__ __align__(16) u16 sAh[128 * 32];
    __shared__ __align__(16) u16 sBh[128 * 32];
    __shared__ __align__(16) u16 sAl[AL ? 128 * 32 : 8];
    __shared__ __align__(16) u16 sBl[BL ? 128 * 32 : 8];

    const int tid = threadIdx.x;
    const int lane = tid & 63, wave = tid >> 6;
    const int wr = wave >> 1, wc = wave & 1;
    // bijective XCD swizzle (nwg % 8 == 0 for all our grids)
    const int nwgx = gridDim.x;
    const int nwg = nwgx * gridDim.y;
    int wg = blockIdx.y * nwgx + blockIdx.x;
    wg = (wg & 7) * (nwg >> 3) + (wg >> 3);
    const int m0 = (wg / nwgx) * 128, n0 = (wg % nwgx) * 128;
    const int fr = lane & 15, fk = lane >> 4;

    v4f acc[4][4];
#pragma unroll
    for (int i = 0; i < 4; ++i)
#pragma unroll
        for (int j = 0; j < 4; ++j) acc[i][j] = (v4f){0.f, 0.f, 0.f, 0.f};

    // staging: 512 chunks of 16B per matrix; chunk c -> LDS byte c*16 (linear),
    // so the wave-uniform-dest constraint of global_load_lds is met exactly.
    const int c0 = tid, c1 = tid + 256;
    const int r0 = c0 >> 2, kg0 = c0 & 3, r1 = c1 >> 2, kg1 = c1 & 3;
    const int cw0 = (tid & ~63) * 8;          // wave-uniform LDS elem base, half 0
    const int cw1 = cw0 + 256 * 8;            // half 1

    for (int kk = 0; kk < K; kk += 32) {
        const size_t a0 = (size_t)(m0 + r0) * K + kk + kg0 * 8;
        const size_t a1 = (size_t)(m0 + r1) * K + kk + kg1 * 8;
        const size_t b0 = (size_t)(n0 + r0) * K + kk + kg0 * 8;
        const size_t b1 = (size_t)(n0 + r1) * K + kk + kg1 * 8;
        gload_lds16(Ahi + a0, sAh + cw0);
        gload_lds16(Ahi + a1, sAh + cw1);
        gload_lds16(Bhi + b0, sBh + cw0);
        gload_lds16(Bhi + b1, sBh + cw1);
        if constexpr (AL) {
            gload_lds16(Alo + a0, sAl + cw0);
            gload_lds16(Alo + a1, sAl + cw1);
        }
        if constexpr (BL) {
            gload_lds16(Blo + b0, sBl + cw0);
            gload_lds16(Blo + b1, sBl + cw1);
        }
        __syncthreads();   // drains vmcnt: all global_load_lds landed

        v8s ah[4], bh[4], al[4], bl[4];
#pragma unroll
        for (int mt = 0; mt < 4; ++mt) {
            const int row = wr * 64 + mt * 16 + fr;
            const int idx = row * 32 + fk * 8;
            ah[mt] = *(const v8s*)(sAh + idx);
            if constexpr (AL) al[mt] = *(const v8s*)(sAl + idx);
        }
#pragma unroll
        for (int nt = 0; nt < 4; ++nt) {
            const int row = wc * 64 + nt * 16 + fr;
            const int idx = row * 32 + fk * 8;
            bh[nt] = *(const v8s*)(sBh + idx);
            if constexpr (BL) bl[nt] = *(const v8s*)(sBl + idx);
        }
#pragma unroll
        for (int mt = 0; mt < 4; ++mt)
#pragma unroll
            for (int nt = 0; nt < 4; ++nt) {
                acc[mt][nt] = mf(ah[mt], bh[nt], acc[mt][nt]);
                if constexpr (AL) acc[mt][nt] = mf(al[mt], bh[nt], acc[mt][nt]);
                if constexpr (BL) acc[mt][nt] = mf(ah[mt], bl[nt], acc[mt][nt]);
            }
        __syncthreads();
    }

    // epilogue: D layout col = lane&15, row = (lane>>4)*4 + p  [m89-verified]
#pragma unroll
    for (int nt = 0; nt < 4; ++nt) {
        const int col = n0 + wc * 64 + nt * 16 + fr;
        float bsum = bias1 ? bias1[col] : 0.f;
        if (bias2) bsum += bias2[col];
#pragma unroll
        for (int mt = 0; mt < 4; ++mt) {
            const int rowb = m0 + wr * 64 + mt * 16 + fk * 4;
#pragma unroll
            for (int p = 0; p < 4; ++p) {
                const int row = rowb + p;
                const float v = acc[mt][nt][p] + bsum;
                if constexpr (MODE == 2) {
                    const int t = row >> 5, b = row & 31;
                    Cout[(size_t)b * ((size_t)Tn * Vn) + (size_t)t * Vn + col] = v;
                } else if constexpr (MODE == 1) {
                    const int q = col >> 10, j = col & 1023;
                    const int bidw = j >> 2, rloc = (j & 3) * 4 + q;
                    Cout[(size_t)bidw * ((size_t)MR * 16) + (size_t)row * 16 + rloc] = v;
                } else {
                    Cout[(size_t)row * N + col] = v;
                }
            }
        }
    }
}

// ---------------- windowed per-wave wait + block signal (R15) ----------------
// R14 analysis: wave w consumes h ONLY from producer blocks [w*32, w*32+32)
// (KT b0 = wave*32 + K*8 + fk*2 <= wave*32+31). So the wait needs no block-wide
// barrier: lanes 0-31 of each wave poll that wave's 32 producer flags, wave
// reconverges, compiler fence stops load hoisting. HW ordering unchanged from the
// R6-R14 validated chain: producer drains vmcnt(0) (signal's entry __syncthreads)
// before the relaxed flag store; consumer h addresses are phase-unique -> no stale
// lines. The remaining 2 __syncthreads/phase (red-ready + signal-entry) still gate
// red reuse across phases.
DEVINL void wait_window(unsigned* flags, unsigned tgt, int wave, int lane) {
    if (lane < 32) {
        unsigned* p = flags + (size_t)(wave * 32 + lane) * 16;
        while (__hip_atomic_load(p, __ATOMIC_RELAXED, __HIP_MEMORY_SCOPE_AGENT) < tgt)
            __builtin_amdgcn_s_sleep(0);
    }
    asm volatile("" ::: "memory");   // no hoisting of h loads above the poll
}
DEVINL void signal_phase(unsigned* flags, unsigned val) {
    __syncthreads();   // drains vmcnt(0): sc1 h-stores visible chip-wide
    if (threadIdx.x == 0)
        __hip_atomic_store(&flags[blockIdx.x * 16], val, __ATOMIC_RELAXED, __HIP_MEMORY_SCOPE_AGENT);
}

// ---- named-register weight pinning (4 KT subtiles per wave, K=128/wave; 96 VGPRs).
// asm "+v" makes each fragment an asm output -> reload from memory is illegal
// (gfx950 unified RF: allocator parks them in AGPRs, invisible to VGPR_Count).
// R13 lesson: pinning is load-bearing — streaming ANY weight matrix thrashes L2
// (128KB/block/phase x 32 blocks/XCD = full L2) and regressed 2x.
#define DECLW(P) v8s P##0, P##1, P##2, P##3
#define LOADW(P, BASE) do { const u16* _b = (BASE) + woff; \
    P##0 = *(const v8s*)(_b);       P##1 = *(const v8s*)(_b + 32); \
    P##2 = *(const v8s*)(_b + 64);  P##3 = *(const v8s*)(_b + 96); } while (0)
#define PINW(P) asm volatile("" : "+v"(P##0), "+v"(P##1), "+v"(P##2), "+v"(P##3))

// ---- block-major h fragment load: h stored [t][bid][cb 0..31][cu 0..3].
// For k-subtile kt, lane (fr,fk) needs k = wave*128 + kt*32 + fk*8 + e (e=0..7)
// -> bids {b0, b0+1} with b0 = wave*32 + kt*8 + fk*2; element (cb,k) lives at
// bid*128 + cb*4 + (k&3). Two 8B loads per fragment; coalesced.
#define LD8(B, B0, RO) cat8(*(const v4s*)((B) + (size_t)(B0) * 128 + (RO)), \
                            *(const v4s*)((B) + (size_t)(B0) * 128 + 128 + (RO)))

// one K-subtile (32 elems) of the h0-driven MFMAs: L0 (Whh0) + L1 input (Wih1)
#define KT0(K) { \
    const int b0 = wave * 32 + K * 8 + fk * 2; \
    v8s hah = LD8(h0sh, b0, fr4); \
    v8s hal = LD8(h0sl, b0, fr4); \
    v8s hbh = LD8(h0sh, b0, fr4 + 64); \
    v8s hbl = LD8(h0sl, b0, fr4 + 64); \
    if (doL0) { \
        r0a = mf(hah, w0h_##K, r0a); r0a = mf(hal, w0h_##K, r0a); r0a = mf(hah, w0l_##K, r0a); \
        r0b = mf(hbh, w0h_##K, r0b); r0b = mf(hbl, w0h_##K, r0b); r0b = mf(hbh, w0l_##K, r0b); } \
    if (doL1) { \
        r1a = mf(hah, wih_##K, r1a); r1a = mf(hal, wih_##K, r1a); r1a = mf(hah, wil_##K, r1a); \
        r1b = mf(hbh, wih_##K, r1b); r1b = mf(hbl, wih_##K, r1b); r1b = mf(hbh, wil_##K, r1b); } }

// one K-subtile of the h1-driven MFMAs: L1 recurrent (Whh1)
#define KT1(K) { \
    const int b0 = wave * 32 + K * 8 + fk * 2; \
    v8s hah = LD8(h1sh, b0, fr4); \
    v8s hal = LD8(h1sl, b0, fr4); \
    v8s hbh = LD8(h1sh, b0, fr4 + 64); \
    v8s hbl = LD8(h1sl, b0, fr4 + 64); \
    r1a = mf(hah, w1h_##K, r1a); r1a = mf(hal, w1h_##K, r1a); r1a = mf(hah, w1l_##K, r1a); \
    r1b = mf(hbh, w1h_##K, r1b); r1b = mf(hbl, w1h_##K, r1b); r1b = mf(hbh, w1l_##K, r1b); }

// ---------------- merged 2-layer LSTM scan: single flag + windowed wait (R15) ----------
// Phase p: L0 computes t0=p (p<64), L1 computes t1=p-1 (p>=1); both consume h0[p-1],
// L1 also h1[p-2]. Per-wave windowed wait covers both (flag p = phase p-1 fully done
// at that producer). KT0+KT1 issue as one stream; ONE red sync; cells for L0
// (tid<128) and L1 (tid 128-255) run CONCURRENTLY; ONE signal.
__global__ __launch_bounds__(512, 2)
void lstm_scan2(const u16* __restrict__ W0h, const u16* __restrict__ W0l,
                const u16* __restrict__ WIh, const u16* __restrict__ WIl,
                const u16* __restrict__ W1h, const u16* __restrict__ W1l,
                const float* __restrict__ G0,
                const float* __restrict__ bi1, const float* __restrict__ bh1,
                const u16* __restrict__ s0h, const u16* __restrict__ s0l,
                const u16* __restrict__ s1h, const u16* __restrict__ s1l,
                u16* __restrict__ h0ha, u16* __restrict__ h0la,
                u16* __restrict__ h1ha, u16* __restrict__ h1la,
                u16* __restrict__ hs_h, u16* __restrict__ hs_l,
                const float* __restrict__ c0i, const float* __restrict__ c1i,
                float* __restrict__ c0o, float* __restrict__ c1o,
                unsigned* bar, int pbase, int initfs) {
    __shared__ float red0[8][32][17];
    __shared__ float red1[8][32][17];
    const int tid = threadIdx.x, lane = tid & 63, wave = tid >> 6, bid = blockIdx.x;
    const int fr = lane & 15, fk = lane >> 4;
    const int fr4 = fr * 4;
    const size_t woff = (size_t)(bid * 16 + fr) * Hn + wave * 128 + fk * 8;
    unsigned* flags = bar + 16;

    DECLW(w0h_); DECLW(w0l_); DECLW(wih_); DECLW(wil_); DECLW(w1h_); DECLW(w1l_);
    LOADW(w0h_, W0h); LOADW(w0l_, W0l);
    LOADW(wih_, WIh); LOADW(wil_, WIl);
    LOADW(w1h_, W1h); LOADW(w1l_, W1l);
    PINW(w0h_); PINW(w0l_); PINW(wih_); PINW(wil_); PINW(w1h_); PINW(w1l_);

    const int lt = tid & 127, cb = lt >> 2, cu = lt & 3, cj = bid * 4 + cu;
    const bool isL0 = tid < 128;
    const bool isL1 = (tid >= 128) && (tid < 256);
    float creg = 0.f;
    float b1v[4];
    if (isL0) {
        if (initfs) creg = c0i[cb * Hn + cj];
    } else if (isL1) {
        if (initfs) creg = c1i[cb * Hn + cj];
#pragma unroll
        for (int q = 0; q < 4; ++q) b1v[q] = bi1[q * Hn + cj] + bh1[q * Hn + cj];
    }

    for (int p = 0; p <= 64; ++p) {
        const bool doL0 = (p < 64), doL1 = (p >= 1);
        const bool hasH0 = (p > 0) || (initfs != 0);
        const bool hasH1 = doL1 && ((p > 1) || (initfs != 0));
        const u16* h0sh = (p == 0) ? s0h : h0ha + (size_t)(p - 1) * BH;
        const u16* h0sl = (p == 0) ? s0l : h0la + (size_t)(p - 1) * BH;
        const u16* h1sh = (p <= 1) ? s1h : h1ha + (size_t)(p - 2) * BH;
        const u16* h1sl = (p <= 1) ? s1l : h1la + (size_t)(p - 2) * BH;

        // issue G prefetch BEFORE the wait poll (HBM latency hides under detection)
        v4f gq = (v4f){0.f, 0.f, 0.f, 0.f};
        if (isL0 && doL0)
            gq = *(const v4f*)(G0 + (size_t)bid * ((size_t)MR * 16)
                               + (size_t)(p * 32 + cb) * 16 + cu * 4);

        if (p >= 1) wait_window(flags, (unsigned)(pbase + p), wave, lane);

        v4f r0a = {0,0,0,0}, r0b = {0,0,0,0}, r1a = {0,0,0,0}, r1b = {0,0,0,0};
        if (hasH0) {
            KT0(0) KT0(1) KT0(2) KT0(3)
        }
        if (hasH1) {
            KT1(0) KT1(1) KT1(2) KT1(3)
        }
        if (doL0 && hasH0) {
#pragma unroll
            for (int pp = 0; pp < 4; ++pp) {
                red0[wave][fk * 4 + pp][fr]      = r0a[pp];
                red0[wave][fk * 4 + pp + 16][fr] = r0b[pp];
            }
        }
        if (doL1) {
#pragma unroll
            for (int pp = 0; pp < 4; ++pp) {
                red1[wave][fk * 4 + pp][fr]      = r1a[pp];
                red1[wave][fk * 4 + pp + 16][fr] = r1b[pp];
            }
        }
        __syncthreads();   // red0 + red1 ready

        if (isL0) {
            if (doL0) {
                float gv[4];
#pragma unroll
                for (int q = 0; q < 4; ++q) {
                    const int rr = q * 4 + cu;
                    float s = 0.f;
                    if (hasH0) {
#pragma unroll
                        for (int wv = 0; wv < 8; ++wv) s += red0[wv][cb][rr];
                    }
                    gv[q] = s + gq[q];
                }
                const float gi = sigm(gv[0]), gf = sigm(gv[1]);
                const float gg = tanh_fast(gv[2]), go = sigm(gv[3]);
                creg = gf * creg + gi * gg;
                const float h = go * tanh_fast(creg);
                u16 hh, hl; split2(h, hh, hl);
                // pack unit-pairs via shfl; even-cu lane stores u32 write-through (sc1).
                // Block-major layout: u32 idx = bid*64 + cb*2 + cu/2 (256B contiguous/block)
                const unsigned prh = (unsigned)(u16)__shfl_xor((int)hh, 1);
                const unsigned prl = (unsigned)(u16)__shfl_xor((int)hl, 1);
                if ((cu & 1) == 0) {
                    const size_t ho2 = (size_t)p * (BH / 2) + bid * 64 + cb * 2 + (cu >> 1);
                    __hip_atomic_store((unsigned*)h0ha + ho2, (prh << 16) | hh,
                                       __ATOMIC_RELAXED, __HIP_MEMORY_SCOPE_AGENT);
                    __hip_atomic_store((unsigned*)h0la + ho2, (prl << 16) | hl,
                                       __ATOMIC_RELAXED, __HIP_MEMORY_SCOPE_AGENT);
                }
                if (p == 63) {
                    c0o[cb * Hn + cj] = creg;            // cross-kernel: end-of-kernel flush
                    if (hs_h) {
                        hs_h[bid * 128 + cb * 4 + cu] = hh;   // block-major seed copy
                        hs_l[bid * 128 + cb * 4 + cu] = hl;
                    }
                }
            }
        } else if (isL1) {
            if (doL1) {
                const int t1 = p - 1;
                float gv[4];
#pragma unroll
                for (int q = 0; q < 4; ++q) {
                    const int rr = q * 4 + cu;
                    float s = b1v[q];
#pragma unroll
                    for (int wv = 0; wv < 8; ++wv) s += red1[wv][cb][rr];
                    gv[q] = s;
                }
                const float gi = sigm(gv[0]), gf = sigm(gv[1]);
                const float gg = tanh_fast(gv[2]), go = sigm(gv[3]);
                creg = gf * creg + gi * gg;
                const float h = go * tanh_fast(creg);
                u16 hh, hl; split2(h, hh, hl);
                const unsigned prh = (unsigned)(u16)__shfl_xor((int)hh, 1);
                const unsigned prl = (unsigned)(u16)__shfl_xor((int)hl, 1);
                if ((cu & 1) == 0) {
                    const size_t ho2 = (size_t)t1 * (BH / 2) + bid * 64 + cb * 2 + (cu >> 1);
                    __hip_atomic_store((unsigned*)h1ha + ho2, (prh << 16) | hh,
                                       __ATOMIC_RELAXED, __HIP_MEMORY_SCOPE_AGENT);
                    __hip_atomic_store((unsigned*)h1la + ho2, (prl << 16) | hl,
                                       __ATOMIC_RELAXED, __HIP_MEMORY_SCOPE_AGENT);
                }
                if (t1 == 63) c1o[cb * Hn + cj] = creg;  // cross-kernel: end-of-kernel flush
            }
        }
        signal_phase(flags, (unsigned)(pbase + p + 1));
    }
}

// ---------------- host launch ----------------
extern "C" void kernel_launch(void* const* d_in, const int* in_sizes, int n_in,
                              void* d_out, int out_size, void* d_ws, size_t ws_size,
                              hipStream_t stream) {
    (void)in_sizes; (void)n_in; (void)out_size; (void)ws_size;
    const int*   input_seq  = (const int*)d_in[0];
    const int*   target_seq = (const int*)d_in[1];
    const float* emb  = (const float*)d_in[2];
    const float* fc_W = (const float*)d_in[3];
    const float* fc_b = (const float*)d_in[4];
    // [0]=enc L0, [1]=enc L1, [2]=dec L0, [3]=dec L1
    const float* W_ih[4] = {(const float*)d_in[5],  (const float*)d_in[9],
                            (const float*)d_in[13], (const float*)d_in[17]};
    const float* W_hh[4] = {(const float*)d_in[6],  (const float*)d_in[10],
                            (const float*)d_in[14], (const float*)d_in[18]};
    const float* b_ih[4] = {(const float*)d_in[7],  (const float*)d_in[11],
                            (const float*)d_in[15], (const float*)d_in[19]};
    const float* b_hh[4] = {(const float*)d_in[8],  (const float*)d_in[12],
                            (const float*)d_in[16], (const float*)d_in[20]};

    char* w = (char*)d_ws;
    size_t off = 0;
    auto alloc = [&](size_t bytes) {
        void* p = (void*)(w + off);
        off += (bytes + 255) & ~(size_t)255;
        return p;
    };
    unsigned* bar = (unsigned*)alloc(BAR_U32 * 4);
    float* G   = (float*)alloc((size_t)MR * FH * 4);     // 33.6 MB, permuted [bid][m][16]
    u16* W0h   = (u16*)alloc((size_t)FH * Hn * 2);       // Whh(L0) perm hi
    u16* W0l   = (u16*)alloc((size_t)FH * Hn * 2);
    u16* WIh   = (u16*)alloc((size_t)FH * Hn * 2);       // Wih(L1) perm hi
    u16* WIl   = (u16*)alloc((size_t)FH * Hn * 2);
    u16* W1h   = (u16*)alloc((size_t)FH * Hn * 2);       // Whh(L1) perm hi
    u16* W1l   = (u16*)alloc((size_t)FH * Hn * 2);
    u16* SWh   = (u16*)alloc((size_t)FH * Hn * 2);       // Wih(L0) split (GEMM B)
    u16* SWl   = (u16*)alloc((size_t)FH * Hn * 2);
    u16* Xh    = (u16*)alloc((size_t)MR * En * 2);       // gathered embeddings hi
    u16* Xl    = (u16*)alloc((size_t)MR * En * 2);
    u16* hAh   = (u16*)alloc((size_t)Tn * BH * 2);       // layer-0 h block-major, hi
    u16* hAl   = (u16*)alloc((size_t)Tn * BH * 2);
    u16* hBh   = (u16*)alloc((size_t)Tn * BH * 2);       // layer-1 h block-major, hi
    u16* hBl   = (u16*)alloc((size_t)Tn * BH * 2);
    u16* hs0h  = (u16*)alloc((size_t)BH * 2);            // enc h0 final seed (block-major)
    u16* hs0l  = (u16*)alloc((size_t)BH * 2);
    float* c0  = (float*)alloc((size_t)BH * 4);          // cell-state carries
    float* c1  = (float*)alloc((size_t)BH * 4);
    u16* hFh   = (u16*)alloc((size_t)MR * Hn * 2);       // dec h1 row-major for FC
    u16* hFl   = (u16*)alloc((size_t)MR * Hn * 2);
    // fc_W bf16 aliases the dead G..WIl region after dec scan (needs 65.5 MB <= 67.2 MB)
    u16* fWh = (u16*)G;

    bar_init<<<1, 256, 0, stream>>>(bar);

    auto scan = [&](const u16* s0hp, const u16* s0lp, const u16* s1hp, const u16* s1lp,
                    u16* hsh, u16* hsl, const float* bi1, const float* bh1,
                    int pbase, int fs) {
        const u16 *a0=W0h,*a1=W0l,*a2=WIh,*a3=WIl,*a4=W1h,*a5=W1l;
        const float* Gp = G;
        u16 *p0=hAh,*p1=hAl,*p2=hBh,*p3=hBl;
        const float *ci0=c0,*ci1=c1; float *co0=c0,*co1=c1;
        unsigned* bp = bar;
        void* args[] = {(void*)&a0,(void*)&a1,(void*)&a2,(void*)&a3,(void*)&a4,(void*)&a5,
                        (void*)&Gp,(void*)&bi1,(void*)&bh1,
                        (void*)&s0hp,(void*)&s0lp,(void*)&s1hp,(void*)&s1lp,
                        (void*)&p0,(void*)&p1,(void*)&p2,(void*)&p3,
                        (void*)&hsh,(void*)&hsl,
                        (void*)&ci0,(void*)&ci1,(void*)&co0,(void*)&co1,
                        (void*)&bp,(void*)&pbase,(void*)&fs};
        if (hipLaunchCooperativeKernel((void*)lstm_scan2, dim3(256), dim3(512),
                                       args, 0, stream) != hipSuccess) {
            // fallback: 256 blocks x 8 waves co-resident on 256 CUs
            lstm_scan2<<<dim3(256), dim3(512), 0, stream>>>(
                W0h, W0l, WIh, WIl, W1h, W1l, G, bi1, bh1,
                s0hp, s0lp, s1hp, s1lp, hAh, hAl, hBh, hBl, hsh, hsl,
                c0, c1, c0, c1, bar, pbase, fs);
        }
    };

    const size_t lastT = (size_t)63 * BH;

    // ---- encoder: G0 = emb(input) @ Wih0^T + biases, then merged L0+L1 scan ----
    gather_split<<<MR, 256, 0, stream>>>(emb, input_seq, 0, Xh, Xl);
    split_w<<<2048, 256, 0, stream>>>(W_ih[0], SWh, SWl, FH * En / 4);
    gemm_bt<3, 1><<<dim3(FH / 128, MR / 128), 256, 0, stream>>>(
        Xh, Xl, SWh, SWl, b_ih[0], b_hh[0], G, MR, FH, En);
    perm_split<<<FH, 256, 0, stream>>>(W_hh[0], W0h, W0l);
    perm_split<<<FH, 256, 0, stream>>>(W_ih[1], WIh, WIl);
    perm_split<<<FH, 256, 0, stream>>>(W_hh[1], W1h, W1l);
    scan(hs0h, hs0l, hs0h, hs0l, hs0h, hs0l, b_ih[1], b_hh[1], 0, 0);

    // ---- decoder: teacher forcing inputs = [<sos>, target[:,:-1]] ----
    gather_split<<<MR, 256, 0, stream>>>(emb, target_seq, 1, Xh, Xl);
    split_w<<<2048, 256, 0, stream>>>(W_ih[2], SWh, SWl, FH * En / 4);
    gemm_bt<3, 1><<<dim3(FH / 128, MR / 128), 256, 0, stream>>>(
        Xh, Xl, SWh, SWl, b_ih[2], b_hh[2], G, MR, FH, En);
    perm_split<<<FH, 256, 0, stream>>>(W_hh[2], W0h, W0l);
    perm_split<<<FH, 256, 0, stream>>>(W_ih[3], WIh, WIl);
    perm_split<<<FH, 256, 0, stream>>>(W_hh[3], W1h, W1l);
    // seeds: h0 from fresh copy; h1 from hB[63] (block-major, first touch post-boundary)
    scan(hs0h, hs0l, hBh + lastT, hBl + lastT, nullptr, nullptr,
         b_ih[3], b_hh[3], 65, 1);

    // ---- FC: logits[b][t][v] = dec_h1[t][b][:] . fc_W[v][:] + fc_b[v] ----
    unperm_h<<<MR, 256, 0, stream>>>(hBh, hBl, hFh, hFl);
    split_w<<<2048, 256, 0, stream>>>(fc_W, fWh, nullptr, Vn * Hn / 4);
    gemm_bt<2, 2><<<dim3(Vn / 128, MR / 128), 256, 0, stream>>>(
        hFh, hFl, fWh, nullptr, fc_b, nullptr, (float*)d_out, MR, Vn, Hn);
}